// Round 13
// baseline (251.657 us; speedup 1.0000x reference)
//
#include <hip/hip_runtime.h>
#include <hip/hip_bf16.h>
#include <stdint.h>

// Problem constants (fixed by reference)
#define TSEQ   2048
#define DMODEL 1024
#define NH     16
#define HDIM   64
#define NKVH   4

typedef __attribute__((ext_vector_type(8))) short short8;
typedef __attribute__((ext_vector_type(8))) _Float16 half8;
typedef __attribute__((ext_vector_type(4))) float f32x4;
typedef __hip_bfloat16 bf16;

// async global->LDS, 16B per lane (linear LDS dest = wave base + lane*16)
__device__ __forceinline__ void gload16(const void* g, void* l) {
    __builtin_amdgcn_global_load_lds(
        (const __attribute__((address_space(1))) uint32_t*)g,
        (__attribute__((address_space(3))) uint32_t*)l, 16, 0, 0);
}

// priority comparator: higher score wins; tie -> lower index wins (matches jax top_k)
__device__ __forceinline__ bool pgt(float as, int ai, float bs, int bi) {
    return (as > bs) || (as == bs && ai < bi);
}

// full bitonic sort across 64 lanes, ascending by priority (validated R6)
__device__ __forceinline__ void bsort(float& s, int& i, int lane) {
#pragma unroll
    for (int k = 2; k <= 64; k <<= 1) {
#pragma unroll
        for (int j = k >> 1; j > 0; j >>= 1) {
            float os = __shfl_xor(s, j, 64);
            int   oi = __shfl_xor(i, j, 64);
            bool lower = (lane & j) == 0;
            bool asc   = (lane & k) == 0;
            bool wmin  = (lower == asc);
            bool takeo = (pgt(s, i, os, oi) == wmin);
            if (takeo) { s = os; i = oi; }
        }
    }
}

// bitonic -> ascending cleanup (6 stages) (validated R6)
__device__ __forceinline__ void bmerge(float& s, int& i, int lane) {
#pragma unroll
    for (int j = 32; j > 0; j >>= 1) {
        float os = __shfl_xor(s, j, 64);
        int   oi = __shfl_xor(i, j, 64);
        bool lower = (lane & j) == 0;
        bool takeo = (pgt(s, i, os, oi) == lower);
        if (takeo) { s = os; i = oi; }
    }
}

// ---- fused prep: fp32->bf16 convert x, transpose-convert the three weights ----
__global__ __launch_bounds__(256) void prep_kernel(
    const float* __restrict__ x, const float* __restrict__ wq,
    const float* __restrict__ wkv, const float* __restrict__ wo,
    bf16* __restrict__ cx, bf16* __restrict__ cwqT,
    bf16* __restrict__ cwkvT, bf16* __restrict__ cwoT)
{
    __shared__ float tile[32][33];
    const int bid = blockIdx.x;
    if (bid < 1024) {
        const size_t i0 = (size_t)bid * 256 + threadIdx.x;
        for (size_t i = i0; i < 2097152; i += 262144) cx[i] = __float2bfloat16(x[i]);
        return;
    }
    const float* in; bf16* out; int R, Cc, bx, by;
    if (bid < 2048) {        // wq: 1024x1024
        int idx = bid - 1024; in = wq; out = cwqT; R = 1024; Cc = 1024;
        bx = (idx & 31) << 5; by = (idx >> 5) << 5;
    } else if (bid < 2560) { // wkv: 1024x512
        int idx = bid - 2048; in = wkv; out = cwkvT; R = 1024; Cc = 512;
        bx = (idx & 15) << 5; by = (idx >> 4) << 5;
    } else {                 // wo: 1024x1024
        int idx = bid - 2560; in = wo; out = cwoT; R = 1024; Cc = 1024;
        bx = (idx & 31) << 5; by = (idx >> 5) << 5;
    }
    const int tx = threadIdx.x & 31, ty = threadIdx.x >> 5;   // 32 x 8
#pragma unroll
    for (int i = 0; i < 32; i += 8)
        tile[ty + i][tx] = in[(size_t)(by + ty + i) * Cc + bx + tx];
    __syncthreads();
#pragma unroll
    for (int i = 0; i < 32; i += 8)
        out[(size_t)(bx + ty + i) * R + by + tx] = __float2bfloat16(tile[tx][ty + i]);
}

// ---- 128x128-tile MFMA GEMM (m93 structure): 4 waves 2x2, each 64x64
// (acc[4][4] f32x4), BK=64, 32KB LDS, XOR-swizzled both sides, gload16
// staging. 32 MFMA per 2 barriers (4x the 64-tile ratio).
// MODE 0: out-proj: C = A@cwoT^T + bo (fp32)
// MODE 1: fused QKV: bx<8 -> Q (RMSnorm*0.125 -> qh); bx>=8 -> KV
//         (cols<256: k RMSnorm -> kh; else v -> vbuf). Epilogue math identical
//         to the validated R10/R12 64-tile versions.
template<int MODE>
__global__ __launch_bounds__(256, 2) void gemm128(
    const bf16* __restrict__ A, const bf16* __restrict__ BT1,
    const bf16* __restrict__ BT2, const float* __restrict__ bias1,
    const float* __restrict__ bias2, float* __restrict__ C,
    _Float16* __restrict__ qh, _Float16* __restrict__ kh,
    float* __restrict__ vbuf, const float* __restrict__ qn_w,
    const float* __restrict__ kn_w)
{
    __shared__ short As[128][64];   // 16KB
    __shared__ short Bs[128][64];   // 16KB
    const int tid = threadIdx.x;
    const int bx = blockIdx.x;
    const bool isQ = (MODE == 1) && (bx < 8);
    const bf16* BT = (MODE == 0) ? BT1 : (isQ ? BT1 : BT2);
    const float* bias = (MODE == 0) ? bias1 : (isQ ? bias1 : bias2);
    const int n0 = (MODE == 0 || isQ) ? bx * 128 : (bx - 8) * 128;
    const int K = 1024;
    const int m0 = blockIdx.y * 128;
    const int w = tid >> 6, lane = tid & 63;
    const int q4 = lane >> 4, mm = lane & 15;
    const int wr = w >> 1, wc = w & 1;
    f32x4 acc[4][4];
#pragma unroll
    for (int mr = 0; mr < 4; ++mr)
#pragma unroll
        for (int nc = 0; nc < 4; ++nc) acc[mr][nc] = (f32x4){0.f, 0.f, 0.f, 0.f};

    // staging: thread covers rows {ar+32i}, 16B each; dest linear = tid*16.
    // 32*i keeps (row&7) constant -> one swizzled slot per thread.
    const int ar = tid >> 3, sl = tid & 7;
    const int ss = sl ^ (ar & 7);
    const short* Agb = (const short*)A + (size_t)(m0 + ar) * K + ss * 8;
    const short* Bgb = (const short*)BT + (size_t)(n0 + ar) * K + ss * 8;

    const short* Asf = &As[0][0];
    const short* Bsf = &Bs[0][0];
    const int xm = mm & 7;

    for (int k0 = 0; k0 < K; k0 += 64) {
        __syncthreads();
#pragma unroll
        for (int i = 0; i < 4; ++i) {
            gload16(Agb + (size_t)32 * i * K + k0, &As[ar + 32 * i][sl * 8]);
            gload16(Bgb + (size_t)32 * i * K + k0, &Bs[ar + 32 * i][sl * 8]);
        }
        __syncthreads();   // drains vmcnt (compiler emits it before s_barrier)
#pragma unroll
        for (int hf = 0; hf < 2; ++hf) {
            const int slot = ((hf * 4 + q4) ^ xm) * 8;
            short8 af[4], bf[4];
#pragma unroll
            for (int mr = 0; mr < 4; ++mr)
                af[mr] = *(const short8*)(Asf + (wr * 64 + mr * 16 + mm) * 64 + slot);
#pragma unroll
            for (int nc = 0; nc < 4; ++nc)
                bf[nc] = *(const short8*)(Bsf + (wc * 64 + nc * 16 + mm) * 64 + slot);
#pragma unroll
            for (int mr = 0; mr < 4; ++mr)
#pragma unroll
                for (int nc = 0; nc < 4; ++nc)
                    acc[mr][nc] = __builtin_amdgcn_mfma_f32_16x16x32_bf16(
                        af[mr], bf[nc], acc[mr][nc], 0, 0, 0);
        }
    }

    const int colbase = n0 + wc * 64;   // this wave's 64-col (one-head) tile
    if (MODE == 0) {
#pragma unroll
        for (int mr = 0; mr < 4; ++mr)
#pragma unroll
            for (int nc = 0; nc < 4; ++nc)
#pragma unroll
                for (int r = 0; r < 4; ++r)
                    C[(size_t)(m0 + wr * 64 + mr * 16 + q4 * 4 + r) * DMODEL
                      + colbase + nc * 16 + mm]
                        = acc[mr][nc][r] + bias[colbase + nc * 16 + mm];
    } else {
#pragma unroll
        for (int mr = 0; mr < 4; ++mr) {
#pragma unroll
            for (int r = 0; r < 4; ++r) {
                const int row = m0 + wr * 64 + mr * 16 + q4 * 4 + r;
                float vv[4];
#pragma unroll
                for (int nc = 0; nc < 4; ++nc)
                    vv[nc] = acc[mr][nc][r] + bias[colbase + nc * 16 + mm];
                if (isQ || colbase < 256) {
                    float ssum = 0.f;
#pragma unroll
                    for (int nc = 0; nc < 4; ++nc) ssum += vv[nc] * vv[nc];
#pragma unroll
                    for (int j = 8; j >= 1; j >>= 1) ssum += __shfl_xor(ssum, j, 64);
                    float rs = 1.0f / sqrtf(ssum * (1.0f / 64.0f) + 1e-8f);
                    if (isQ) {
#pragma unroll
                        for (int nc = 0; nc < 4; ++nc) {
                            int d = nc * 16 + mm;
                            qh[(size_t)row * DMODEL + colbase + d] =
                                (_Float16)(vv[nc] * rs * qn_w[d] * 0.125f);
                        }
                    } else {
                        int kvh = colbase >> 6;
#pragma unroll
                        for (int nc = 0; nc < 4; ++nc) {
                            int d = nc * 16 + mm;
                            kh[((size_t)kvh * TSEQ + row) * HDIM + d] =
                                (_Float16)(vv[nc] * rs * kn_w[d]);
                        }
                    }
                } else {   // v block
                    int kvh = (colbase - 256) >> 6;
#pragma unroll
                    for (int nc = 0; nc < 4; ++nc)
                        vbuf[((size_t)kvh * TSEQ + row) * HDIM + nc * 16 + mm] = vv[nc];
                }
            }
        }
    }
}

// ---- fused MFMA scores + exact top-64 + softmax + V gather ----
// R10 version verbatim (measured 140us): static heavy-first grid, 4-wave
// block, cooperative chunk production, candidate buffer, static window +
// per-row runtime gate, bitonic top-64.
__global__ __launch_bounds__(256, 4) void attn_kernel(
    const _Float16* __restrict__ qh, const _Float16* __restrict__ kh,
    const float* __restrict__ vbuf, bf16* __restrict__ ybuf,
    const float* __restrict__ kn_w)
{
    __shared__ float Sg[2][16][68];      // [buf][qrow][key] one chunk
    __shared__ float cbS[16][128];       // per-row candidate scores
    __shared__ int   cbI[16][128];       // per-row candidate indices
    __shared__ int   eminS[4];           // per-wave earliest needed key
    const int tid = threadIdx.x;
    const int w = tid >> 6, lane = tid & 63;
    const int mm = lane & 15, q4 = lane >> 4;
    const int h = 15 - (blockIdx.x >> 7);            // heavy (low-slope) heads first
    const int t0 = (127 - (blockIdx.x & 127)) << 4;  // long rows first within head
    const int kvh = h >> 2;
    const float slope = exp2f(-((float)h) * (8.0f / 15.0f));
    const _Float16* kbase = kh + (size_t)kvh * TSEQ * HDIM;
    const int nch = (t0 + 15) >> 6;

    // max |kn_w| (wave-uniform)
    float kw = fabsf(kn_w[lane]);
#pragma unroll
    for (int j = 32; j > 0; j >>= 1) kw = fmaxf(kw, __shfl_xor(kw, j, 64));
    const float kfac = 8.0f * kw * 1.001f;

    // per-row exact bound B and window for this wave's rows r = 4w+rr
    float Brow[4];
    int em = 0x7fffffff;
#pragma unroll
    for (int rr = 0; rr < 4; ++rr) {
        const int r = 4 * w + rr;
        float qe = (float)qh[(size_t)(t0 + r) * DMODEL + h * HDIM + lane];
        float qs = qe * qe;
#pragma unroll
        for (int j = 32; j > 0; j >>= 1) qs += __shfl_xor(qs, j, 64);
        Brow[rr] = sqrtf(qs) * kfac + 1e-3f;
        float Dw = 2.0f * Brow[rr] / slope + 64.0f;
        int e = (int)floorf((float)(t0 + r) - Dw);
        em = min(em, e);
    }
    if (lane == 0) eminS[w] = em;

    // Q fragments (f16, 1/8 scale folded). A-frag: row=lane&15, k=(lane>>4)*8..+7
    const _Float16* qp = qh + (size_t)(t0 + mm) * DMODEL + h * HDIM + q4 * 8;
    half8 qf0 = *(const half8*)(qp);        // d 0..31
    half8 qf1 = *(const half8*)(qp + 32);   // d 32..63

    // prologue: produce chunk nch into buffer 0 (wave w -> keys w*16..w*16+15)
    {
        const int jb = nch << 6;
        const _Float16* kp = kbase + ((size_t)(jb + w * 16 + mm)) * HDIM + q4 * 8;
        half8 b0 = *(const half8*)(kp);
        half8 b1 = *(const half8*)(kp + 32);
        f32x4 a = __builtin_amdgcn_mfma_f32_16x16x32_f16(
            qf0, b0, (f32x4){0.f, 0.f, 0.f, 0.f}, 0, 0, 0);
        a = __builtin_amdgcn_mfma_f32_16x16x32_f16(qf1, b1, a, 0, 0, 0);
        // C layout: col=lane&15 (key), row=(lane>>4)*4+reg (query)
#pragma unroll
        for (int rr = 0; rr < 4; ++rr)
            Sg[0][q4 * 4 + rr][w * 16 + mm] = a[rr];
    }
    __syncthreads();

    // block-uniform earliest chunk (conservative: min over all rows)
    int em4 = min(min(eminS[0], eminS[1]), min(eminS[2], eminS[3]));
    const int c_min = (em4 > 0) ? (em4 >> 6) : 0;

    float cs[4]; int ci[4]; float thr[4]; int cnt[4];
#pragma unroll
    for (int rr = 0; rr < 4; ++rr) { cs[rr] = -1e30f; ci[rr] = 0; thr[rr] = -1e30f; cnt[rr] = 0; }

    int p = 0;
    for (int c = nch; c >= c_min; --c) {
        // issue next chunk's K loads early (hide L2 latency under merge)
        const int cn = c - 1;
        half8 b0, b1;
        if (cn >= c_min) {
            const _Float16* kp = kbase + ((size_t)((cn << 6) + w * 16 + mm)) * HDIM + q4 * 8;
            b0 = *(const half8*)(kp);
            b1 = *(const half8*)(kp + 32);
        }
        // merge chunk c for this wave's 4 rows
        const int jb = c << 6;
#pragma unroll
        for (int rr = 0; rr < 4; ++rr) {
            const int r = 4 * w + rr;
            // per-row runtime prune (validated): chunk can't reach th
            int dm = (t0 + r - 63) - jb;
            float dmin = (float)(dm > 0 ? dm : 0);
            if (Brow[rr] - slope * dmin < thr[rr]) continue;
            float sr = Sg[p][r][lane];
            int dist = (t0 + r) - (jb + lane);
            float s = sr - slope * (float)dist;
            bool pass = (dist >= 0) && (s >= thr[rr]);
            unsigned long long mk = __ballot(pass);
            if (mk) {
                int rank = __popcll(mk & ((1ull << lane) - 1ull));
                if (pass) { cbS[r][cnt[rr] + rank] = s; cbI[r][cnt[rr] + rank] = jb + lane; }
                cnt[rr] += __popcll(mk);
                if (cnt[rr] >= 64) {
                    float ns = cbS[r][lane];
                    int   ni = cbI[r][lane];
                    bsort(ns, ni, lane);
                    float rsv = __shfl_xor(ns, 63, 64);   // descending view
                    int   riv = __shfl_xor(ni, 63, 64);
                    if (pgt(rsv, riv, cs[rr], ci[rr])) { cs[rr] = rsv; ci[rr] = riv; }
                    bmerge(cs[rr], ci[rr], lane);          // restore ascending
                    thr[rr] = __shfl(cs[rr], 0, 64);
                    int rem = cnt[rr] - 64;
                    float ms = 0.f; int mi = 0;
                    if (lane < rem) { ms = cbS[r][64 + lane]; mi = cbI[r][64 + lane]; }
                    if (lane < rem) { cbS[r][lane] = ms; cbI[r][lane] = mi; }
                    cnt[rr] = rem;
                }
            }
        }
        // produce next chunk into the other buffer
        if (cn >= c_min) {
            f32x4 a = __builtin_amdgcn_mfma_f32_16x16x32_f16(
                qf0, b0, (f32x4){0.f, 0.f, 0.f, 0.f}, 0, 0, 0);
            a = __builtin_amdgcn_mfma_f32_16x16x32_f16(qf1, b1, a, 0, 0, 0);
#pragma unroll
            for (int rr = 0; rr < 4; ++rr)
                Sg[p ^ 1][q4 * 4 + rr][w * 16 + mm] = a[rr];
        }
        p ^= 1;
        __syncthreads();
    }

    // epilogue per row: flush, softmax, V gather, store
    const float* vb = vbuf + (size_t)kvh * TSEQ * HDIM + lane;
#pragma unroll
    for (int rr = 0; rr < 4; ++rr) {
        const int r = 4 * w + rr;
        if (cnt[rr] > 0) {
            float ns = (lane < cnt[rr]) ? cbS[r][lane] : -2e30f;
            int   ni = (lane < cnt[rr]) ? cbI[r][lane] : 0;
            bsort(ns, ni, lane);
            float rsv = __shfl_xor(ns, 63, 64);
            int   riv = __shfl_xor(ni, 63, 64);
            if (pgt(rsv, riv, cs[rr], ci[rr])) { cs[rr] = rsv; ci[rr] = riv; }
            bmerge(cs[rr], ci[rr], lane);
        }
        // softmax over kept 64 (pads -1e30 -> weight 0); max at lane 63
        float msx = __shfl(cs[rr], 63, 64);
        bool valid = cs[rr] > -1e29f;
        float pr = valid ? __expf(cs[rr] - msx) : 0.f;
        float l = pr;
#pragma unroll
        for (int j2 = 32; j2 > 0; j2 >>= 1) l += __shfl_xor(l, j2, 64);
        float wgt = pr / l;
        int widx = valid ? ci[rr] : 0;
        float acc = 0.f;
#pragma unroll 8
        for (int i = 0; i < 64; ++i) {
            float wv = __shfl(wgt, i, 64);
            int  ix = __shfl(widx, i, 64);
            acc += wv * vb[(size_t)ix * HDIM];
        }
        ybuf[(size_t)(t0 + r) * DMODEL + h * HDIM + lane] = __float2bfloat16(acc);
    }
}

extern "C" void kernel_launch(void* const* d_in, const int* in_sizes, int n_in,
                              void* d_out, int out_size, void* d_ws, size_t ws_size,
                              hipStream_t stream)
{
    // d_in order: x, wq, bq, wkv, bkv, wo, bo, qn_w, kn_w  (all fp32)
    const float* x    = (const float*)d_in[0];
    const float* wq   = (const float*)d_in[1];
    const float* bq   = (const float*)d_in[2];
    const float* wkv  = (const float*)d_in[3];
    const float* bkv  = (const float*)d_in[4];
    const float* wo   = (const float*)d_in[5];
    const float* bo   = (const float*)d_in[6];
    const float* qn_w = (const float*)d_in[7];
    const float* kn_w = (const float*)d_in[8];
    char* ws = (char*)d_ws;
    // ws layout (28 MB):
    // cx bf16 4M @0 | cwqT 2M @4M | cwkvT 1M @6M | cwoT 2M @7M |
    // qh f16 4M @9M | kh f16 1M @21M | vbuf fp32 2M @22M |
    // ybuf bf16 4M @24M..28M  (no overlaps)
    bf16*      cx    = (bf16*)(ws);
    bf16*      cwqT  = (bf16*)(ws + ((size_t)4  << 20));   // [1024][1024] (n,k)
    bf16*      cwkvT = (bf16*)(ws + ((size_t)6  << 20));   // [512][1024]  (n,k)
    bf16*      cwoT  = (bf16*)(ws + ((size_t)7  << 20));   // [1024][1024] (n,k)
    _Float16*  qh    = (_Float16*)(ws + ((size_t)9  << 20));
    _Float16*  kh    = (_Float16*)(ws + ((size_t)21 << 20));
    float*     vbuf  = (float*)(ws + ((size_t)22 << 20));
    bf16*      ybuf  = (bf16*)(ws + ((size_t)24 << 20));
    float*     out   = (float*)d_out;   // fp32 output

    prep_kernel<<<3584, 256, 0, stream>>>(x, wq, wkv, wo, cx, cwqT, cwkvT, cwoT);
    gemm128<1><<<dim3(12, TSEQ / 128), 256, 0, stream>>>(
        cx, cwqT, cwkvT, bq, bkv, nullptr, qh, kh, vbuf, qn_w, kn_w);
    attn_kernel<<<NH * (TSEQ / 16), 256, 0, stream>>>(qh, kh, vbuf, ybuf, kn_w);
    gemm128<0><<<dim3(8, TSEQ / 128), 256, 0, stream>>>(
        ybuf, cwoT, nullptr, bo, nullptr, out, nullptr, nullptr, nullptr,
        nullptr, nullptr);
}

// Round 15
// 234.668 us; speedup vs baseline: 1.0724x; 1.0724x over previous
//
#include <hip/hip_runtime.h>
#include <hip/hip_bf16.h>
#include <stdint.h>

// Problem constants (fixed by reference)
#define TSEQ   2048
#define DMODEL 1024
#define NH     16
#define HDIM   64
#define NKVH   4

typedef __attribute__((ext_vector_type(8))) short short8;
typedef __attribute__((ext_vector_type(8))) _Float16 half8;
typedef __attribute__((ext_vector_type(4))) float f32x4;
typedef __hip_bfloat16 bf16;

// async global->LDS, 16B per lane (linear LDS dest = wave base + lane*16)
__device__ __forceinline__ void gload16(const void* g, void* l) {
    __builtin_amdgcn_global_load_lds(
        (const __attribute__((address_space(1))) uint32_t*)g,
        (__attribute__((address_space(3))) uint32_t*)l, 16, 0, 0);
}

// priority comparator: higher score wins; tie -> lower index wins (matches jax top_k)
__device__ __forceinline__ bool pgt(float as, int ai, float bs, int bi) {
    return (as > bs) || (as == bs && ai < bi);
}

// full bitonic sort across 64 lanes, ascending by priority (validated R6)
__device__ __forceinline__ void bsort(float& s, int& i, int lane) {
#pragma unroll
    for (int k = 2; k <= 64; k <<= 1) {
#pragma unroll
        for (int j = k >> 1; j > 0; j >>= 1) {
            float os = __shfl_xor(s, j, 64);
            int   oi = __shfl_xor(i, j, 64);
            bool lower = (lane & j) == 0;
            bool asc   = (lane & k) == 0;
            bool wmin  = (lower == asc);
            bool takeo = (pgt(s, i, os, oi) == wmin);
            if (takeo) { s = os; i = oi; }
        }
    }
}

// bitonic -> ascending cleanup (6 stages) (validated R6)
__device__ __forceinline__ void bmerge(float& s, int& i, int lane) {
#pragma unroll
    for (int j = 32; j > 0; j >>= 1) {
        float os = __shfl_xor(s, j, 64);
        int   oi = __shfl_xor(i, j, 64);
        bool lower = (lane & j) == 0;
        bool takeo = (pgt(s, i, os, oi) == lower);
        if (takeo) { s = os; i = oi; }
    }
}

// ---- fused prep: fp32->bf16 convert x, transpose-convert the three weights ----
__global__ __launch_bounds__(256) void prep_kernel(
    const float* __restrict__ x, const float* __restrict__ wq,
    const float* __restrict__ wkv, const float* __restrict__ wo,
    bf16* __restrict__ cx, bf16* __restrict__ cwqT,
    bf16* __restrict__ cwkvT, bf16* __restrict__ cwoT)
{
    __shared__ float tile[32][33];
    const int bid = blockIdx.x;
    if (bid < 1024) {
        const size_t i0 = (size_t)bid * 256 + threadIdx.x;
        for (size_t i = i0; i < 2097152; i += 262144) cx[i] = __float2bfloat16(x[i]);
        return;
    }
    const float* in; bf16* out; int R, Cc, bx, by;
    if (bid < 2048) {        // wq: 1024x1024
        int idx = bid - 1024; in = wq; out = cwqT; R = 1024; Cc = 1024;
        bx = (idx & 31) << 5; by = (idx >> 5) << 5;
    } else if (bid < 2560) { // wkv: 1024x512
        int idx = bid - 2048; in = wkv; out = cwkvT; R = 1024; Cc = 512;
        bx = (idx & 15) << 5; by = (idx >> 4) << 5;
    } else {                 // wo: 1024x1024
        int idx = bid - 2560; in = wo; out = cwoT; R = 1024; Cc = 1024;
        bx = (idx & 31) << 5; by = (idx >> 5) << 5;
    }
    const int tx = threadIdx.x & 31, ty = threadIdx.x >> 5;   // 32 x 8
#pragma unroll
    for (int i = 0; i < 32; i += 8)
        tile[ty + i][tx] = in[(size_t)(by + ty + i) * Cc + bx + tx];
    __syncthreads();
#pragma unroll
    for (int i = 0; i < 32; i += 8)
        out[(size_t)(bx + ty + i) * R + by + tx] = __float2bfloat16(tile[tx][ty + i]);
}

// ---- fused Q+KV GEMM (validated R12): one launch; bx<16 = Q (RMSnorm*0.125
//      -> qh), bx>=16 = KV (k: RMSnorm -> kh; v: fp32 -> vbuf). 64x64 tile.
__global__ __launch_bounds__(256) void gemm_qkv(
    const bf16* __restrict__ A, const bf16* __restrict__ BTq,
    const bf16* __restrict__ BTkv, const float* __restrict__ bq,
    const float* __restrict__ bkv, _Float16* __restrict__ qh,
    _Float16* __restrict__ kh, float* __restrict__ vbuf,
    const float* __restrict__ qn_w, const float* __restrict__ kn_w)
{
    __shared__ short As[64][64];
    __shared__ short Bs[64][64];
    const int tid = threadIdx.x;
    const int bx = blockIdx.x;
    const bool isQ = bx < 16;
    const bf16* BT = isQ ? BTq : BTkv;
    const float* bias = isQ ? bq : bkv;
    const float* wn = isQ ? qn_w : kn_w;
    const int n0 = (isQ ? bx : bx - 16) * 64;
    const int K = 1024;
    const int m0 = blockIdx.y * 64;
    const int w = tid >> 6, lane = tid & 63;
    const int q4 = lane >> 4, mm = lane & 15;
    f32x4 acc[4];
#pragma unroll
    for (int nb = 0; nb < 4; ++nb) acc[nb] = (f32x4){0.f, 0.f, 0.f, 0.f};

    const int ar = tid >> 3;
    const int sslot = (tid & 7) ^ (ar & 7);
    const short* Ag = (const short*)A + (size_t)(m0 + ar) * K + sslot * 8;
    const short* Ag2 = (const short*)A + (size_t)(m0 + ar + 32) * K + ((tid & 7) ^ ((ar + 32) & 7)) * 8;
    const short* Bg = (const short*)BT + (size_t)(n0 + ar) * K + sslot * 8;
    const short* Bg2 = (const short*)BT + (size_t)(n0 + ar + 32) * K + ((tid & 7) ^ ((ar + 32) & 7)) * 8;

    const int xm = mm & 7;
    const short* Asf = (const short*)As;
    const short* Bsf = (const short*)Bs;
    const int aoff0 = (w * 16 + mm) * 64 + ((q4 ^ xm)) * 8;
    const int aoff1 = (w * 16 + mm) * 64 + (((4 + q4) ^ xm)) * 8;
    int boff0[4], boff1[4];
#pragma unroll
    for (int nb = 0; nb < 4; ++nb) {
        boff0[nb] = (nb * 16 + mm) * 64 + ((q4 ^ xm)) * 8;
        boff1[nb] = (nb * 16 + mm) * 64 + (((4 + q4) ^ xm)) * 8;
    }

    for (int k0 = 0; k0 < K; k0 += 64) {
        __syncthreads();
        gload16(Ag + k0, &As[ar][(tid & 7) * 8]);
        gload16(Ag2 + k0, &As[ar + 32][(tid & 7) * 8]);
        gload16(Bg + k0, &Bs[ar][(tid & 7) * 8]);
        gload16(Bg2 + k0, &Bs[ar + 32][(tid & 7) * 8]);
        __syncthreads();
        short8 af0 = *(const short8*)(Asf + aoff0);
        short8 af1 = *(const short8*)(Asf + aoff1);
#pragma unroll
        for (int nb = 0; nb < 4; ++nb) {
            short8 b0 = *(const short8*)(Bsf + boff0[nb]);
            short8 b1 = *(const short8*)(Bsf + boff1[nb]);
            acc[nb] = __builtin_amdgcn_mfma_f32_16x16x32_bf16(af0, b0, acc[nb], 0, 0, 0);
            acc[nb] = __builtin_amdgcn_mfma_f32_16x16x32_bf16(af1, b1, acc[nb], 0, 0, 0);
        }
    }

    float vv[4][4];
#pragma unroll
    for (int nb = 0; nb < 4; ++nb)
#pragma unroll
        for (int r = 0; r < 4; ++r)
            vv[nb][r] = acc[nb][r] + bias[n0 + nb * 16 + mm];

    if (isQ || n0 < 256) {
        // per-row RMS norm over the 64-col head tile
#pragma unroll
        for (int r = 0; r < 4; ++r) {
            float ss = 0.f;
#pragma unroll
            for (int nb = 0; nb < 4; ++nb) ss += vv[nb][r] * vv[nb][r];
#pragma unroll
            for (int j = 8; j >= 1; j >>= 1) ss += __shfl_xor(ss, j, 64);
            float rs = 1.0f / sqrtf(ss * (1.0f / 64.0f) + 1e-8f);
            int row = m0 + w * 16 + q4 * 4 + r;
            if (isQ) {
#pragma unroll
                for (int nb = 0; nb < 4; ++nb) {
                    int d = nb * 16 + mm;
                    qh[(size_t)row * DMODEL + n0 + d] =
                        (_Float16)(vv[nb][r] * rs * wn[d] * 0.125f);
                }
            } else {
                int kvh = n0 >> 6;
#pragma unroll
                for (int nb = 0; nb < 4; ++nb) {
                    int d = nb * 16 + mm;
                    kh[((size_t)kvh * TSEQ + row) * HDIM + d] =
                        (_Float16)(vv[nb][r] * rs * wn[d]);
                }
            }
        }
    } else {   // v block
        int kvh = (n0 - 256) >> 6;
#pragma unroll
        for (int r = 0; r < 4; ++r) {
            int row = m0 + w * 16 + q4 * 4 + r;
#pragma unroll
            for (int nb = 0; nb < 4; ++nb)
                vbuf[((size_t)kvh * TSEQ + row) * HDIM + nb * 16 + mm] = vv[nb][r];
        }
    }
}

// ---- out projection GEMM (validated R12: 64x64 tile, MODE 0 epilogue) ----
__global__ __launch_bounds__(256) void gemm_out(
    const bf16* __restrict__ A, const bf16* __restrict__ BT,
    const float* __restrict__ bias, float* __restrict__ C, int M, int N, int K)
{
    __shared__ short As[64][64];
    __shared__ short Bs[64][64];
    const int tid = threadIdx.x;
    const int m0 = blockIdx.y * 64, n0 = blockIdx.x * 64;
    const int w = tid >> 6, lane = tid & 63;
    const int q4 = lane >> 4, mm = lane & 15;
    f32x4 acc[4];
#pragma unroll
    for (int nb = 0; nb < 4; ++nb) acc[nb] = (f32x4){0.f, 0.f, 0.f, 0.f};

    const int ar = tid >> 3;
    const int sslot = (tid & 7) ^ (ar & 7);
    const short* Ag = (const short*)A + (size_t)(m0 + ar) * K + sslot * 8;
    const short* Ag2 = (const short*)A + (size_t)(m0 + ar + 32) * K + ((tid & 7) ^ ((ar + 32) & 7)) * 8;
    const short* Bg = (const short*)BT + (size_t)(n0 + ar) * K + sslot * 8;
    const short* Bg2 = (const short*)BT + (size_t)(n0 + ar + 32) * K + ((tid & 7) ^ ((ar + 32) & 7)) * 8;

    const int xm = mm & 7;
    const short* Asf = (const short*)As;
    const short* Bsf = (const short*)Bs;
    const int aoff0 = (w * 16 + mm) * 64 + ((q4 ^ xm)) * 8;
    const int aoff1 = (w * 16 + mm) * 64 + (((4 + q4) ^ xm)) * 8;
    int boff0[4], boff1[4];
#pragma unroll
    for (int nb = 0; nb < 4; ++nb) {
        boff0[nb] = (nb * 16 + mm) * 64 + ((q4 ^ xm)) * 8;
        boff1[nb] = (nb * 16 + mm) * 64 + (((4 + q4) ^ xm)) * 8;
    }

    for (int k0 = 0; k0 < K; k0 += 64) {
        __syncthreads();
        gload16(Ag + k0, &As[ar][(tid & 7) * 8]);
        gload16(Ag2 + k0, &As[ar + 32][(tid & 7) * 8]);
        gload16(Bg + k0, &Bs[ar][(tid & 7) * 8]);
        gload16(Bg2 + k0, &Bs[ar + 32][(tid & 7) * 8]);
        __syncthreads();
        short8 af0 = *(const short8*)(Asf + aoff0);
        short8 af1 = *(const short8*)(Asf + aoff1);
#pragma unroll
        for (int nb = 0; nb < 4; ++nb) {
            short8 b0 = *(const short8*)(Bsf + boff0[nb]);
            short8 b1 = *(const short8*)(Bsf + boff1[nb]);
            acc[nb] = __builtin_amdgcn_mfma_f32_16x16x32_bf16(af0, b0, acc[nb], 0, 0, 0);
            acc[nb] = __builtin_amdgcn_mfma_f32_16x16x32_bf16(af1, b1, acc[nb], 0, 0, 0);
        }
    }
#pragma unroll
    for (int nb = 0; nb < 4; ++nb)
#pragma unroll
        for (int r = 0; r < 4; ++r)
            C[(size_t)(m0 + w * 16 + q4 * 4 + r) * N + n0 + nb * 16 + mm]
                = acc[nb][r] + bias[n0 + nb * 16 + mm];
}

// ---- fused MFMA scores + exact top-64 + softmax + V gather ----
// R10/R13 version verbatim (measured 139-140us): static heavy-first grid,
// 4-wave block, cooperative chunk production, candidate buffer, static
// window + per-row runtime gate, bitonic top-64.
__global__ __launch_bounds__(256, 4) void attn_kernel(
    const _Float16* __restrict__ qh, const _Float16* __restrict__ kh,
    const float* __restrict__ vbuf, bf16* __restrict__ ybuf,
    const float* __restrict__ kn_w)
{
    __shared__ float Sg[2][16][68];      // [buf][qrow][key] one chunk
    __shared__ float cbS[16][128];       // per-row candidate scores
    __shared__ int   cbI[16][128];       // per-row candidate indices
    __shared__ int   eminS[4];           // per-wave earliest needed key
    const int tid = threadIdx.x;
    const int w = tid >> 6, lane = tid & 63;
    const int mm = lane & 15, q4 = lane >> 4;
    const int h = 15 - (blockIdx.x >> 7);            // heavy (low-slope) heads first
    const int t0 = (127 - (blockIdx.x & 127)) << 4;  // long rows first within head
    const int kvh = h >> 2;
    const float slope = exp2f(-((float)h) * (8.0f / 15.0f));
    const _Float16* kbase = kh + (size_t)kvh * TSEQ * HDIM;
    const int nch = (t0 + 15) >> 6;

    // max |kn_w| (wave-uniform)
    float kw = fabsf(kn_w[lane]);
#pragma unroll
    for (int j = 32; j > 0; j >>= 1) kw = fmaxf(kw, __shfl_xor(kw, j, 64));
    const float kfac = 8.0f * kw * 1.001f;

    // per-row exact bound B and window for this wave's rows r = 4w+rr
    float Brow[4];
    int em = 0x7fffffff;
#pragma unroll
    for (int rr = 0; rr < 4; ++rr) {
        const int r = 4 * w + rr;
        float qe = (float)qh[(size_t)(t0 + r) * DMODEL + h * HDIM + lane];
        float qs = qe * qe;
#pragma unroll
        for (int j = 32; j > 0; j >>= 1) qs += __shfl_xor(qs, j, 64);
        Brow[rr] = sqrtf(qs) * kfac + 1e-3f;
        float Dw = 2.0f * Brow[rr] / slope + 64.0f;
        int e = (int)floorf((float)(t0 + r) - Dw);
        em = min(em, e);
    }
    if (lane == 0) eminS[w] = em;

    // Q fragments (f16, 1/8 scale folded). A-frag: row=lane&15, k=(lane>>4)*8..+7
    const _Float16* qp = qh + (size_t)(t0 + mm) * DMODEL + h * HDIM + q4 * 8;
    half8 qf0 = *(const half8*)(qp);        // d 0..31
    half8 qf1 = *(const half8*)(qp + 32);   // d 32..63

    // prologue: produce chunk nch into buffer 0 (wave w -> keys w*16..w*16+15)
    {
        const int jb = nch << 6;
        const _Float16* kp = kbase + ((size_t)(jb + w * 16 + mm)) * HDIM + q4 * 8;
        half8 b0 = *(const half8*)(kp);
        half8 b1 = *(const half8*)(kp + 32);
        f32x4 a = __builtin_amdgcn_mfma_f32_16x16x32_f16(
            qf0, b0, (f32x4){0.f, 0.f, 0.f, 0.f}, 0, 0, 0);
        a = __builtin_amdgcn_mfma_f32_16x16x32_f16(qf1, b1, a, 0, 0, 0);
        // C layout: col=lane&15 (key), row=(lane>>4)*4+reg (query)
#pragma unroll
        for (int rr = 0; rr < 4; ++rr)
            Sg[0][q4 * 4 + rr][w * 16 + mm] = a[rr];
    }
    __syncthreads();

    // block-uniform earliest chunk (conservative: min over all rows)
    int em4 = min(min(eminS[0], eminS[1]), min(eminS[2], eminS[3]));
    const int c_min = (em4 > 0) ? (em4 >> 6) : 0;

    float cs[4]; int ci[4]; float thr[4]; int cnt[4];
#pragma unroll
    for (int rr = 0; rr < 4; ++rr) { cs[rr] = -1e30f; ci[rr] = 0; thr[rr] = -1e30f; cnt[rr] = 0; }

    int p = 0;
    for (int c = nch; c >= c_min; --c) {
        // issue next chunk's K loads early (hide L2 latency under merge)
        const int cn = c - 1;
        half8 b0, b1;
        if (cn >= c_min) {
            const _Float16* kp = kbase + ((size_t)((cn << 6) + w * 16 + mm)) * HDIM + q4 * 8;
            b0 = *(const half8*)(kp);
            b1 = *(const half8*)(kp + 32);
        }
        // merge chunk c for this wave's 4 rows
        const int jb = c << 6;
#pragma unroll
        for (int rr = 0; rr < 4; ++rr) {
            const int r = 4 * w + rr;
            // per-row runtime prune (validated): chunk can't reach th
            int dm = (t0 + r - 63) - jb;
            float dmin = (float)(dm > 0 ? dm : 0);
            if (Brow[rr] - slope * dmin < thr[rr]) continue;
            float sr = Sg[p][r][lane];
            int dist = (t0 + r) - (jb + lane);
            float s = sr - slope * (float)dist;
            bool pass = (dist >= 0) && (s >= thr[rr]);
            unsigned long long mk = __ballot(pass);
            if (mk) {
                int rank = __popcll(mk & ((1ull << lane) - 1ull));
                if (pass) { cbS[r][cnt[rr] + rank] = s; cbI[r][cnt[rr] + rank] = jb + lane; }
                cnt[rr] += __popcll(mk);
                if (cnt[rr] >= 64) {
                    float ns = cbS[r][lane];
                    int   ni = cbI[r][lane];
                    bsort(ns, ni, lane);
                    float rsv = __shfl_xor(ns, 63, 64);   // descending view
                    int   riv = __shfl_xor(ni, 63, 64);
                    if (pgt(rsv, riv, cs[rr], ci[rr])) { cs[rr] = rsv; ci[rr] = riv; }
                    bmerge(cs[rr], ci[rr], lane);          // restore ascending
                    thr[rr] = __shfl(cs[rr], 0, 64);
                    int rem = cnt[rr] - 64;
                    float ms = 0.f; int mi = 0;
                    if (lane < rem) { ms = cbS[r][64 + lane]; mi = cbI[r][64 + lane]; }
                    if (lane < rem) { cbS[r][lane] = ms; cbI[r][lane] = mi; }
                    cnt[rr] = rem;
                }
            }
        }
        // produce next chunk into the other buffer
        if (cn >= c_min) {
            f32x4 a = __builtin_amdgcn_mfma_f32_16x16x32_f16(
                qf0, b0, (f32x4){0.f, 0.f, 0.f, 0.f}, 0, 0, 0);
            a = __builtin_amdgcn_mfma_f32_16x16x32_f16(qf1, b1, a, 0, 0, 0);
#pragma unroll
            for (int rr = 0; rr < 4; ++rr)
                Sg[p ^ 1][q4 * 4 + rr][w * 16 + mm] = a[rr];
        }
        p ^= 1;
        __syncthreads();
    }

    // epilogue per row: flush, softmax, V gather, store
    const float* vb = vbuf + (size_t)kvh * TSEQ * HDIM + lane;
#pragma unroll
    for (int rr = 0; rr < 4; ++rr) {
        const int r = 4 * w + rr;
        if (cnt[rr] > 0) {
            float ns = (lane < cnt[rr]) ? cbS[r][lane] : -2e30f;
            int   ni = (lane < cnt[rr]) ? cbI[r][lane] : 0;
            bsort(ns, ni, lane);
            float rsv = __shfl_xor(ns, 63, 64);
            int   riv = __shfl_xor(ni, 63, 64);
            if (pgt(rsv, riv, cs[rr], ci[rr])) { cs[rr] = rsv; ci[rr] = riv; }
            bmerge(cs[rr], ci[rr], lane);
        }
        // softmax over kept 64 (pads -1e30 -> weight 0); max at lane 63
        float msx = __shfl(cs[rr], 63, 64);
        bool valid = cs[rr] > -1e29f;
        float pr = valid ? __expf(cs[rr] - msx) : 0.f;
        float l = pr;
#pragma unroll
        for (int j2 = 32; j2 > 0; j2 >>= 1) l += __shfl_xor(l, j2, 64);
        float wgt = pr / l;
        int widx = valid ? ci[rr] : 0;
        float acc = 0.f;
#pragma unroll 8
        for (int i = 0; i < 64; ++i) {
            float wv = __shfl(wgt, i, 64);
            int  ix = __shfl(widx, i, 64);
            acc += wv * vb[(size_t)ix * HDIM];
        }
        ybuf[(size_t)(t0 + r) * DMODEL + h * HDIM + lane] = __float2bfloat16(acc);
    }
}

extern "C" void kernel_launch(void* const* d_in, const int* in_sizes, int n_in,
                              void* d_out, int out_size, void* d_ws, size_t ws_size,
                              hipStream_t stream)
{
    // d_in order: x, wq, bq, wkv, bkv, wo, bo, qn_w, kn_w  (all fp32)
    const float* x    = (const float*)d_in[0];
    const float* wq   = (const float*)d_in[1];
    const float* bq   = (const float*)d_in[2];
    const float* wkv  = (const float*)d_in[3];
    const float* bkv  = (const float*)d_in[4];
    const float* wo   = (const float*)d_in[5];
    const float* bo   = (const float*)d_in[6];
    const float* qn_w = (const float*)d_in[7];
    const float* kn_w = (const float*)d_in[8];
    char* ws = (char*)d_ws;
    // ws layout (28 MB):
    // cx bf16 4M @0 | cwqT 2M @4M | cwkvT 1M @6M | cwoT 2M @7M |
    // qh f16 4M @9M | kh f16 1M @21M | vbuf fp32 2M @22M |
    // ybuf bf16 4M @24M..28M  (no overlaps)
    bf16*      cx    = (bf16*)(ws);
    bf16*      cwqT  = (bf16*)(ws + ((size_t)4  << 20));   // [1024][1024] (n,k)
    bf16*      cwkvT = (bf16*)(ws + ((size_t)6  << 20));   // [512][1024]  (n,k)
    bf16*      cwoT  = (bf16*)(ws + ((size_t)7  << 20));   // [1024][1024] (n,k)
    _Float16*  qh    = (_Float16*)(ws + ((size_t)9  << 20));
    _Float16*  kh    = (_Float16*)(ws + ((size_t)21 << 20));
    float*     vbuf  = (float*)(ws + ((size_t)22 << 20));
    bf16*      ybuf  = (bf16*)(ws + ((size_t)24 << 20));
    float*     out   = (float*)d_out;   // fp32 output

    prep_kernel<<<3584, 256, 0, stream>>>(x, wq, wkv, wo, cx, cwqT, cwkvT, cwoT);
    gemm_qkv<<<dim3(24, TSEQ / 64), 256, 0, stream>>>(
        cx, cwqT, cwkvT, bq, bkv, qh, kh, vbuf, qn_w, kn_w);
    attn_kernel<<<NH * (TSEQ / 16), 256, 0, stream>>>(qh, kh, vbuf, ybuf, kn_w);
    gemm_out<<<dim3(DMODEL / 64, TSEQ / 64), 256, 0, stream>>>(
        ybuf, cwoT, bo, out, TSEQ, DMODEL, DMODEL);
}

// Round 16
// 232.724 us; speedup vs baseline: 1.0814x; 1.0084x over previous
//
#include <hip/hip_runtime.h>
#include <hip/hip_bf16.h>
#include <stdint.h>

// Problem constants (fixed by reference)
#define TSEQ   2048
#define DMODEL 1024
#define NH     16
#define HDIM   64
#define NKVH   4

typedef __attribute__((ext_vector_type(8))) short short8;
typedef __attribute__((ext_vector_type(8))) _Float16 half8;
typedef __attribute__((ext_vector_type(4))) float f32x4;
typedef __hip_bfloat16 bf16;

// async global->LDS, 16B per lane (linear LDS dest = wave base + lane*16)
__device__ __forceinline__ void gload16(const void* g, void* l) {
    __builtin_amdgcn_global_load_lds(
        (const __attribute__((address_space(1))) uint32_t*)g,
        (__attribute__((address_space(3))) uint32_t*)l, 16, 0, 0);
}

// priority comparator: higher score wins; tie -> lower index wins (matches jax top_k)
__device__ __forceinline__ bool pgt(float as, int ai, float bs, int bi) {
    return (as > bs) || (as == bs && ai < bi);
}

// full bitonic sort across 64 lanes, ascending by priority (validated R6)
__device__ __forceinline__ void bsort(float& s, int& i, int lane) {
#pragma unroll
    for (int k = 2; k <= 64; k <<= 1) {
#pragma unroll
        for (int j = k >> 1; j > 0; j >>= 1) {
            float os = __shfl_xor(s, j, 64);
            int   oi = __shfl_xor(i, j, 64);
            bool lower = (lane & j) == 0;
            bool asc   = (lane & k) == 0;
            bool wmin  = (lower == asc);
            bool takeo = (pgt(s, i, os, oi) == wmin);
            if (takeo) { s = os; i = oi; }
        }
    }
}

// bitonic -> ascending cleanup (6 stages) (validated R6)
__device__ __forceinline__ void bmerge(float& s, int& i, int lane) {
#pragma unroll
    for (int j = 32; j > 0; j >>= 1) {
        float os = __shfl_xor(s, j, 64);
        int   oi = __shfl_xor(i, j, 64);
        bool lower = (lane & j) == 0;
        bool takeo = (pgt(s, i, os, oi) == lower);
        if (takeo) { s = os; i = oi; }
    }
}

// ---- fused prep: fp32->bf16 convert x, transpose-convert the three weights ----
__global__ __launch_bounds__(256) void prep_kernel(
    const float* __restrict__ x, const float* __restrict__ wq,
    const float* __restrict__ wkv, const float* __restrict__ wo,
    bf16* __restrict__ cx, bf16* __restrict__ cwqT,
    bf16* __restrict__ cwkvT, bf16* __restrict__ cwoT)
{
    __shared__ float tile[32][33];
    const int bid = blockIdx.x;
    if (bid < 1024) {
        const size_t i0 = (size_t)bid * 256 + threadIdx.x;
        for (size_t i = i0; i < 2097152; i += 262144) cx[i] = __float2bfloat16(x[i]);
        return;
    }
    const float* in; bf16* out; int R, Cc, bx, by;
    if (bid < 2048) {        // wq: 1024x1024
        int idx = bid - 1024; in = wq; out = cwqT; R = 1024; Cc = 1024;
        bx = (idx & 31) << 5; by = (idx >> 5) << 5;
    } else if (bid < 2560) { // wkv: 1024x512
        int idx = bid - 2048; in = wkv; out = cwkvT; R = 1024; Cc = 512;
        bx = (idx & 15) << 5; by = (idx >> 4) << 5;
    } else {                 // wo: 1024x1024
        int idx = bid - 2560; in = wo; out = cwoT; R = 1024; Cc = 1024;
        bx = (idx & 31) << 5; by = (idx >> 5) << 5;
    }
    const int tx = threadIdx.x & 31, ty = threadIdx.x >> 5;   // 32 x 8
#pragma unroll
    for (int i = 0; i < 32; i += 8)
        tile[ty + i][tx] = in[(size_t)(by + ty + i) * Cc + bx + tx];
    __syncthreads();
#pragma unroll
    for (int i = 0; i < 32; i += 8)
        out[(size_t)(bx + ty + i) * R + by + tx] = __float2bfloat16(tile[tx][ty + i]);
}

// ---- fused Q+KV GEMM (validated R12/R15): one launch; bx<16 = Q
//      (RMSnorm*0.125 -> qh), bx>=16 = KV (k: RMSnorm -> kh; v -> vbuf).
__global__ __launch_bounds__(256) void gemm_qkv(
    const bf16* __restrict__ A, const bf16* __restrict__ BTq,
    const bf16* __restrict__ BTkv, const float* __restrict__ bq,
    const float* __restrict__ bkv, _Float16* __restrict__ qh,
    _Float16* __restrict__ kh, float* __restrict__ vbuf,
    const float* __restrict__ qn_w, const float* __restrict__ kn_w)
{
    __shared__ short As[64][64];
    __shared__ short Bs[64][64];
    const int tid = threadIdx.x;
    const int bx = blockIdx.x;
    const bool isQ = bx < 16;
    const bf16* BT = isQ ? BTq : BTkv;
    const float* bias = isQ ? bq : bkv;
    const float* wn = isQ ? qn_w : kn_w;
    const int n0 = (isQ ? bx : bx - 16) * 64;
    const int K = 1024;
    const int m0 = blockIdx.y * 64;
    const int w = tid >> 6, lane = tid & 63;
    const int q4 = lane >> 4, mm = lane & 15;
    f32x4 acc[4];
#pragma unroll
    for (int nb = 0; nb < 4; ++nb) acc[nb] = (f32x4){0.f, 0.f, 0.f, 0.f};

    const int ar = tid >> 3;
    const int sslot = (tid & 7) ^ (ar & 7);
    const short* Ag = (const short*)A + (size_t)(m0 + ar) * K + sslot * 8;
    const short* Ag2 = (const short*)A + (size_t)(m0 + ar + 32) * K + ((tid & 7) ^ ((ar + 32) & 7)) * 8;
    const short* Bg = (const short*)BT + (size_t)(n0 + ar) * K + sslot * 8;
    const short* Bg2 = (const short*)BT + (size_t)(n0 + ar + 32) * K + ((tid & 7) ^ ((ar + 32) & 7)) * 8;

    const int xm = mm & 7;
    const short* Asf = (const short*)As;
    const short* Bsf = (const short*)Bs;
    const int aoff0 = (w * 16 + mm) * 64 + ((q4 ^ xm)) * 8;
    const int aoff1 = (w * 16 + mm) * 64 + (((4 + q4) ^ xm)) * 8;
    int boff0[4], boff1[4];
#pragma unroll
    for (int nb = 0; nb < 4; ++nb) {
        boff0[nb] = (nb * 16 + mm) * 64 + ((q4 ^ xm)) * 8;
        boff1[nb] = (nb * 16 + mm) * 64 + (((4 + q4) ^ xm)) * 8;
    }

    for (int k0 = 0; k0 < K; k0 += 64) {
        __syncthreads();
        gload16(Ag + k0, &As[ar][(tid & 7) * 8]);
        gload16(Ag2 + k0, &As[ar + 32][(tid & 7) * 8]);
        gload16(Bg + k0, &Bs[ar][(tid & 7) * 8]);
        gload16(Bg2 + k0, &Bs[ar + 32][(tid & 7) * 8]);
        __syncthreads();
        short8 af0 = *(const short8*)(Asf + aoff0);
        short8 af1 = *(const short8*)(Asf + aoff1);
#pragma unroll
        for (int nb = 0; nb < 4; ++nb) {
            short8 b0 = *(const short8*)(Bsf + boff0[nb]);
            short8 b1 = *(const short8*)(Bsf + boff1[nb]);
            acc[nb] = __builtin_amdgcn_mfma_f32_16x16x32_bf16(af0, b0, acc[nb], 0, 0, 0);
            acc[nb] = __builtin_amdgcn_mfma_f32_16x16x32_bf16(af1, b1, acc[nb], 0, 0, 0);
        }
    }

    float vv[4][4];
#pragma unroll
    for (int nb = 0; nb < 4; ++nb)
#pragma unroll
        for (int r = 0; r < 4; ++r)
            vv[nb][r] = acc[nb][r] + bias[n0 + nb * 16 + mm];

    if (isQ || n0 < 256) {
        // per-row RMS norm over the 64-col head tile
#pragma unroll
        for (int r = 0; r < 4; ++r) {
            float ss = 0.f;
#pragma unroll
            for (int nb = 0; nb < 4; ++nb) ss += vv[nb][r] * vv[nb][r];
#pragma unroll
            for (int j = 8; j >= 1; j >>= 1) ss += __shfl_xor(ss, j, 64);
            float rs = 1.0f / sqrtf(ss * (1.0f / 64.0f) + 1e-8f);
            int row = m0 + w * 16 + q4 * 4 + r;
            if (isQ) {
#pragma unroll
                for (int nb = 0; nb < 4; ++nb) {
                    int d = nb * 16 + mm;
                    qh[(size_t)row * DMODEL + n0 + d] =
                        (_Float16)(vv[nb][r] * rs * wn[d] * 0.125f);
                }
            } else {
                int kvh = n0 >> 6;
#pragma unroll
                for (int nb = 0; nb < 4; ++nb) {
                    int d = nb * 16 + mm;
                    kh[((size_t)kvh * TSEQ + row) * HDIM + d] =
                        (_Float16)(vv[nb][r] * rs * wn[d]);
                }
            }
        }
    } else {   // v block
        int kvh = (n0 - 256) >> 6;
#pragma unroll
        for (int r = 0; r < 4; ++r) {
            int row = m0 + w * 16 + q4 * 4 + r;
#pragma unroll
            for (int nb = 0; nb < 4; ++nb)
                vbuf[((size_t)kvh * TSEQ + row) * HDIM + nb * 16 + mm] = vv[nb][r];
        }
    }
}

// ---- out projection GEMM (validated R12/R15: 64x64 tile) ----
__global__ __launch_bounds__(256) void gemm_out(
    const bf16* __restrict__ A, const bf16* __restrict__ BT,
    const float* __restrict__ bias, float* __restrict__ C, int M, int N, int K)
{
    __shared__ short As[64][64];
    __shared__ short Bs[64][64];
    const int tid = threadIdx.x;
    const int m0 = blockIdx.y * 64, n0 = blockIdx.x * 64;
    const int w = tid >> 6, lane = tid & 63;
    const int q4 = lane >> 4, mm = lane & 15;
    f32x4 acc[4];
#pragma unroll
    for (int nb = 0; nb < 4; ++nb) acc[nb] = (f32x4){0.f, 0.f, 0.f, 0.f};

    const int ar = tid >> 3;
    const int sslot = (tid & 7) ^ (ar & 7);
    const short* Ag = (const short*)A + (size_t)(m0 + ar) * K + sslot * 8;
    const short* Ag2 = (const short*)A + (size_t)(m0 + ar + 32) * K + ((tid & 7) ^ ((ar + 32) & 7)) * 8;
    const short* Bg = (const short*)BT + (size_t)(n0 + ar) * K + sslot * 8;
    const short* Bg2 = (const short*)BT + (size_t)(n0 + ar + 32) * K + ((tid & 7) ^ ((ar + 32) & 7)) * 8;

    const int xm = mm & 7;
    const short* Asf = (const short*)As;
    const short* Bsf = (const short*)Bs;
    const int aoff0 = (w * 16 + mm) * 64 + ((q4 ^ xm)) * 8;
    const int aoff1 = (w * 16 + mm) * 64 + (((4 + q4) ^ xm)) * 8;
    int boff0[4], boff1[4];
#pragma unroll
    for (int nb = 0; nb < 4; ++nb) {
        boff0[nb] = (nb * 16 + mm) * 64 + ((q4 ^ xm)) * 8;
        boff1[nb] = (nb * 16 + mm) * 64 + (((4 + q4) ^ xm)) * 8;
    }

    for (int k0 = 0; k0 < K; k0 += 64) {
        __syncthreads();
        gload16(Ag + k0, &As[ar][(tid & 7) * 8]);
        gload16(Ag2 + k0, &As[ar + 32][(tid & 7) * 8]);
        gload16(Bg + k0, &Bs[ar][(tid & 7) * 8]);
        gload16(Bg2 + k0, &Bs[ar + 32][(tid & 7) * 8]);
        __syncthreads();
        short8 af0 = *(const short8*)(Asf + aoff0);
        short8 af1 = *(const short8*)(Asf + aoff1);
#pragma unroll
        for (int nb = 0; nb < 4; ++nb) {
            short8 b0 = *(const short8*)(Bsf + boff0[nb]);
            short8 b1 = *(const short8*)(Bsf + boff1[nb]);
            acc[nb] = __builtin_amdgcn_mfma_f32_16x16x32_bf16(af0, b0, acc[nb], 0, 0, 0);
            acc[nb] = __builtin_amdgcn_mfma_f32_16x16x32_bf16(af1, b1, acc[nb], 0, 0, 0);
        }
    }
#pragma unroll
    for (int nb = 0; nb < 4; ++nb)
#pragma unroll
        for (int r = 0; r < 4; ++r)
            C[(size_t)(m0 + w * 16 + q4 * 4 + r) * N + n0 + nb * 16 + mm]
                = acc[nb][r] + bias[n0 + nb * 16 + mm];
}

// ---- fused MFMA scores + exact top-64 + softmax + V gather ----
// R10/R13 structure with 8-ROW BLOCKS (occupancy lever): grid 4096, 4 waves,
// wave w owns rows t0+2w, t0+2w+1. LDS ~12.4KB -> residency wave-capped at
// 8 blocks/CU (32 waves, 100% static cap) vs 24 waves before. A-frag loads
// rows t0+(mm&7) (upper 8 dup); lanes q4<2 write the 8 valid C-rows.
// Selection/sort/softmax/gather code per row unchanged (validated).
__global__ __launch_bounds__(256, 8) void attn_kernel(
    const _Float16* __restrict__ qh, const _Float16* __restrict__ kh,
    const float* __restrict__ vbuf, bf16* __restrict__ ybuf,
    const float* __restrict__ kn_w)
{
    __shared__ float Sg[2][8][68];       // [buf][qrow][key] one chunk
    __shared__ float cbS[8][128];        // per-row candidate scores
    __shared__ int   cbI[8][128];        // per-row candidate indices
    __shared__ int   eminS[4];           // per-wave earliest needed key
    const int tid = threadIdx.x;
    const int w = tid >> 6, lane = tid & 63;
    const int mm = lane & 15, q4 = lane >> 4;
    const int h = 15 - (blockIdx.x >> 8);            // heavy (low-slope) heads first
    const int t0 = (255 - (blockIdx.x & 255)) << 3;  // long rows first within head
    const int kvh = h >> 2;
    const float slope = exp2f(-((float)h) * (8.0f / 15.0f));
    const _Float16* kbase = kh + (size_t)kvh * TSEQ * HDIM;
    const int nch = (t0 + 7) >> 6;

    // max |kn_w| (wave-uniform)
    float kw = fabsf(kn_w[lane]);
#pragma unroll
    for (int j = 32; j > 0; j >>= 1) kw = fmaxf(kw, __shfl_xor(kw, j, 64));
    const float kfac = 8.0f * kw * 1.001f;

    // per-row exact bound B and window for this wave's rows r = 2w+rr
    float Brow[2];
    int em = 0x7fffffff;
#pragma unroll
    for (int rr = 0; rr < 2; ++rr) {
        const int r = 2 * w + rr;
        float qe = (float)qh[(size_t)(t0 + r) * DMODEL + h * HDIM + lane];
        float qs = qe * qe;
#pragma unroll
        for (int j = 32; j > 0; j >>= 1) qs += __shfl_xor(qs, j, 64);
        Brow[rr] = sqrtf(qs) * kfac + 1e-3f;
        float Dw = 2.0f * Brow[rr] / slope + 64.0f;
        int e = (int)floorf((float)(t0 + r) - Dw);
        em = min(em, e);
    }
    if (lane == 0) eminS[w] = em;

    // Q fragments: A-frag row mm holds Q row t0+(mm&7) (upper 8 duplicated)
    const _Float16* qp = qh + (size_t)(t0 + (mm & 7)) * DMODEL + h * HDIM + q4 * 8;
    half8 qf0 = *(const half8*)(qp);        // d 0..31
    half8 qf1 = *(const half8*)(qp + 32);   // d 32..63

    // prologue: produce chunk nch into buffer 0 (wave w -> keys w*16..w*16+15)
    {
        const int jb = nch << 6;
        const _Float16* kp = kbase + ((size_t)(jb + w * 16 + mm)) * HDIM + q4 * 8;
        half8 b0 = *(const half8*)(kp);
        half8 b1 = *(const half8*)(kp + 32);
        f32x4 a = __builtin_amdgcn_mfma_f32_16x16x32_f16(
            qf0, b0, (f32x4){0.f, 0.f, 0.f, 0.f}, 0, 0, 0);
        a = __builtin_amdgcn_mfma_f32_16x16x32_f16(qf1, b1, a, 0, 0, 0);
        // C layout: col=lane&15 (key), row=(lane>>4)*4+reg; rows 0..7 valid
        if (q4 < 2) {
#pragma unroll
            for (int rr = 0; rr < 4; ++rr)
                Sg[0][q4 * 4 + rr][w * 16 + mm] = a[rr];
        }
    }
    __syncthreads();

    // block-uniform earliest chunk (conservative: min over all rows)
    int em4 = min(min(eminS[0], eminS[1]), min(eminS[2], eminS[3]));
    const int c_min = (em4 > 0) ? (em4 >> 6) : 0;

    float cs[2]; int ci[2]; float thr[2]; int cnt[2];
#pragma unroll
    for (int rr = 0; rr < 2; ++rr) { cs[rr] = -1e30f; ci[rr] = 0; thr[rr] = -1e30f; cnt[rr] = 0; }

    int p = 0;
    for (int c = nch; c >= c_min; --c) {
        // issue next chunk's K loads early (hide L2 latency under merge)
        const int cn = c - 1;
        half8 b0, b1;
        if (cn >= c_min) {
            const _Float16* kp = kbase + ((size_t)((cn << 6) + w * 16 + mm)) * HDIM + q4 * 8;
            b0 = *(const half8*)(kp);
            b1 = *(const half8*)(kp + 32);
        }
        // merge chunk c for this wave's 2 rows
        const int jb = c << 6;
#pragma unroll
        for (int rr = 0; rr < 2; ++rr) {
            const int r = 2 * w + rr;
            // per-row runtime prune (validated): chunk can't reach th
            int dm = (t0 + r - 63) - jb;
            float dmin = (float)(dm > 0 ? dm : 0);
            if (Brow[rr] - slope * dmin < thr[rr]) continue;
            float sr = Sg[p][r][lane];
            int dist = (t0 + r) - (jb + lane);
            float s = sr - slope * (float)dist;
            bool pass = (dist >= 0) && (s >= thr[rr]);
            unsigned long long mk = __ballot(pass);
            if (mk) {
                int rank = __popcll(mk & ((1ull << lane) - 1ull));
                if (pass) { cbS[r][cnt[rr] + rank] = s; cbI[r][cnt[rr] + rank] = jb + lane; }
                cnt[rr] += __popcll(mk);
                if (cnt[rr] >= 64) {
                    float ns = cbS[r][lane];
                    int   ni = cbI[r][lane];
                    bsort(ns, ni, lane);
                    float rsv = __shfl_xor(ns, 63, 64);   // descending view
                    int   riv = __shfl_xor(ni, 63, 64);
                    if (pgt(rsv, riv, cs[rr], ci[rr])) { cs[rr] = rsv; ci[rr] = riv; }
                    bmerge(cs[rr], ci[rr], lane);          // restore ascending
                    thr[rr] = __shfl(cs[rr], 0, 64);
                    int rem = cnt[rr] - 64;
                    float ms = 0.f; int mi = 0;
                    if (lane < rem) { ms = cbS[r][64 + lane]; mi = cbI[r][64 + lane]; }
                    if (lane < rem) { cbS[r][lane] = ms; cbI[r][lane] = mi; }
                    cnt[rr] = rem;
                }
            }
        }
        // produce next chunk into the other buffer
        if (cn >= c_min) {
            f32x4 a = __builtin_amdgcn_mfma_f32_16x16x32_f16(
                qf0, b0, (f32x4){0.f, 0.f, 0.f, 0.f}, 0, 0, 0);
            a = __builtin_amdgcn_mfma_f32_16x16x32_f16(qf1, b1, a, 0, 0, 0);
            if (q4 < 2) {
#pragma unroll
                for (int rr = 0; rr < 4; ++rr)
                    Sg[p ^ 1][q4 * 4 + rr][w * 16 + mm] = a[rr];
            }
        }
        p ^= 1;
        __syncthreads();
    }

    // epilogue per row: flush, softmax, V gather, store
    const float* vb = vbuf + (size_t)kvh * TSEQ * HDIM + lane;
#pragma unroll
    for (int rr = 0; rr < 2; ++rr) {
        const int r = 2 * w + rr;
        if (cnt[rr] > 0) {
            float ns = (lane < cnt[rr]) ? cbS[r][lane] : -2e30f;
            int   ni = (lane < cnt[rr]) ? cbI[r][lane] : 0;
            bsort(ns, ni, lane);
            float rsv = __shfl_xor(ns, 63, 64);
            int   riv = __shfl_xor(ni, 63, 64);
            if (pgt(rsv, riv, cs[rr], ci[rr])) { cs[rr] = rsv; ci[rr] = riv; }
            bmerge(cs[rr], ci[rr], lane);
        }
        // softmax over kept 64 (pads -1e30 -> weight 0); max at lane 63
        float msx = __shfl(cs[rr], 63, 64);
        bool valid = cs[rr] > -1e29f;
        float pr = valid ? __expf(cs[rr] - msx) : 0.f;
        float l = pr;
#pragma unroll
        for (int j2 = 32; j2 > 0; j2 >>= 1) l += __shfl_xor(l, j2, 64);
        float wgt = pr / l;
        int widx = valid ? ci[rr] : 0;
        float acc = 0.f;
#pragma unroll 8
        for (int i = 0; i < 64; ++i) {
            float wv = __shfl(wgt, i, 64);
            int  ix = __shfl(widx, i, 64);
            acc += wv * vb[(size_t)ix * HDIM];
        }
        ybuf[(size_t)(t0 + r) * DMODEL + h * HDIM + lane] = __float2bfloat16(acc);
    }
}

extern "C" void kernel_launch(void* const* d_in, const int* in_sizes, int n_in,
                              void* d_out, int out_size, void* d_ws, size_t ws_size,
                              hipStream_t stream)
{
    // d_in order: x, wq, bq, wkv, bkv, wo, bo, qn_w, kn_w  (all fp32)
    const float* x    = (const float*)d_in[0];
    const float* wq   = (const float*)d_in[1];
    const float* bq   = (const float*)d_in[2];
    const float* wkv  = (const float*)d_in[3];
    const float* bkv  = (const float*)d_in[4];
    const float* wo   = (const float*)d_in[5];
    const float* bo   = (const float*)d_in[6];
    const float* qn_w = (const float*)d_in[7];
    const float* kn_w = (const float*)d_in[8];
    char* ws = (char*)d_ws;
    // ws layout (28 MB):
    // cx bf16 4M @0 | cwqT 2M @4M | cwkvT 1M @6M | cwoT 2M @7M |
    // qh f16 4M @9M | kh f16 1M @21M | vbuf fp32 2M @22M |
    // ybuf bf16 4M @24M..28M  (no overlaps)
    bf16*      cx    = (bf16*)(ws);
    bf16*      cwqT  = (bf16*)(ws + ((size_t)4  << 20));   // [1024][1024] (n,k)
    bf16*      cwkvT = (bf16*)(ws + ((size_t)6  << 20));   // [512][1024]  (n,k)
    bf16*      cwoT  = (bf16*)(ws + ((size_t)7  << 20));   // [1024][1024] (n,k)
    _Float16*  qh    = (_Float16*)(ws + ((size_t)9  << 20));
    _Float16*  kh    = (_Float16*)(ws + ((size_t)21 << 20));
    float*     vbuf  = (float*)(ws + ((size_t)22 << 20));
    bf16*      ybuf  = (bf16*)(ws + ((size_t)24 << 20));
    float*     out   = (float*)d_out;   // fp32 output

    prep_kernel<<<3584, 256, 0, stream>>>(x, wq, wkv, wo, cx, cwqT, cwkvT, cwoT);
    gemm_qkv<<<dim3(24, TSEQ / 64), 256, 0, stream>>>(
        cx, cwqT, cwkvT, bq, bkv, qh, kh, vbuf, qn_w, kn_w);
    attn_kernel<<<NH * (TSEQ / 8), 256, 0, stream>>>(qh, kh, vbuf, ybuf, kn_w);
    gemm_out<<<dim3(DMODEL / 64, TSEQ / 64), 256, 0, stream>>>(
        ybuf, cwoT, bo, out, TSEQ, DMODEL, DMODEL);
}

// Round 17
// 231.208 us; speedup vs baseline: 1.0884x; 1.0066x over previous
//
#include <hip/hip_runtime.h>
#include <hip/hip_bf16.h>
#include <stdint.h>

// Problem constants (fixed by reference)
#define TSEQ   2048
#define DMODEL 1024
#define NH     16
#define HDIM   64
#define NKVH   4

typedef __attribute__((ext_vector_type(8))) short short8;
typedef __attribute__((ext_vector_type(8))) _Float16 half8;
typedef __attribute__((ext_vector_type(4))) float f32x4;
typedef __hip_bfloat16 bf16;

// async global->LDS, 16B per lane (linear LDS dest = wave base + lane*16)
__device__ __forceinline__ void gload16(const void* g, void* l) {
    __builtin_amdgcn_global_load_lds(
        (const __attribute__((address_space(1))) uint32_t*)g,
        (__attribute__((address_space(3))) uint32_t*)l, 16, 0, 0);
}

// priority comparator: higher score wins; tie -> lower index wins (matches jax top_k)
__device__ __forceinline__ bool pgt(float as, int ai, float bs, int bi) {
    return (as > bs) || (as == bs && ai < bi);
}

// full bitonic sort across 64 lanes, ascending by priority (validated R6)
__device__ __forceinline__ void bsort(float& s, int& i, int lane) {
#pragma unroll
    for (int k = 2; k <= 64; k <<= 1) {
#pragma unroll
        for (int j = k >> 1; j > 0; j >>= 1) {
            float os = __shfl_xor(s, j, 64);
            int   oi = __shfl_xor(i, j, 64);
            bool lower = (lane & j) == 0;
            bool asc   = (lane & k) == 0;
            bool wmin  = (lower == asc);
            bool takeo = (pgt(s, i, os, oi) == wmin);
            if (takeo) { s = os; i = oi; }
        }
    }
}

// bitonic -> ascending cleanup (6 stages) (validated R6)
__device__ __forceinline__ void bmerge(float& s, int& i, int lane) {
#pragma unroll
    for (int j = 32; j > 0; j >>= 1) {
        float os = __shfl_xor(s, j, 64);
        int   oi = __shfl_xor(i, j, 64);
        bool lower = (lane & j) == 0;
        bool takeo = (pgt(s, i, os, oi) == lower);
        if (takeo) { s = os; i = oi; }
    }
}

// ---- fused prep: fp32->bf16 convert x, transpose-convert the three weights ----
__global__ __launch_bounds__(256) void prep_kernel(
    const float* __restrict__ x, const float* __restrict__ wq,
    const float* __restrict__ wkv, const float* __restrict__ wo,
    bf16* __restrict__ cx, bf16* __restrict__ cwqT,
    bf16* __restrict__ cwkvT, bf16* __restrict__ cwoT)
{
    __shared__ float tile[32][33];
    const int bid = blockIdx.x;
    if (bid < 1024) {
        const size_t i0 = (size_t)bid * 256 + threadIdx.x;
        for (size_t i = i0; i < 2097152; i += 262144) cx[i] = __float2bfloat16(x[i]);
        return;
    }
    const float* in; bf16* out; int R, Cc, bx, by;
    if (bid < 2048) {        // wq: 1024x1024
        int idx = bid - 1024; in = wq; out = cwqT; R = 1024; Cc = 1024;
        bx = (idx & 31) << 5; by = (idx >> 5) << 5;
    } else if (bid < 2560) { // wkv: 1024x512
        int idx = bid - 2048; in = wkv; out = cwkvT; R = 1024; Cc = 512;
        bx = (idx & 15) << 5; by = (idx >> 4) << 5;
    } else {                 // wo: 1024x1024
        int idx = bid - 2560; in = wo; out = cwoT; R = 1024; Cc = 1024;
        bx = (idx & 31) << 5; by = (idx >> 5) << 5;
    }
    const int tx = threadIdx.x & 31, ty = threadIdx.x >> 5;   // 32 x 8
#pragma unroll
    for (int i = 0; i < 32; i += 8)
        tile[ty + i][tx] = in[(size_t)(by + ty + i) * Cc + bx + tx];
    __syncthreads();
#pragma unroll
    for (int i = 0; i < 32; i += 8)
        out[(size_t)(bx + ty + i) * R + by + tx] = __float2bfloat16(tile[tx][ty + i]);
}

// ---- fused Q+KV GEMM (validated R12/R15): one launch; bx<16 = Q
//      (RMSnorm*0.125 -> qh), bx>=16 = KV (k: RMSnorm -> kh; v -> vbuf).
__global__ __launch_bounds__(256) void gemm_qkv(
    const bf16* __restrict__ A, const bf16* __restrict__ BTq,
    const bf16* __restrict__ BTkv, const float* __restrict__ bq,
    const float* __restrict__ bkv, _Float16* __restrict__ qh,
    _Float16* __restrict__ kh, float* __restrict__ vbuf,
    const float* __restrict__ qn_w, const float* __restrict__ kn_w)
{
    __shared__ short As[64][64];
    __shared__ short Bs[64][64];
    const int tid = threadIdx.x;
    const int bx = blockIdx.x;
    const bool isQ = bx < 16;
    const bf16* BT = isQ ? BTq : BTkv;
    const float* bias = isQ ? bq : bkv;
    const float* wn = isQ ? qn_w : kn_w;
    const int n0 = (isQ ? bx : bx - 16) * 64;
    const int K = 1024;
    const int m0 = blockIdx.y * 64;
    const int w = tid >> 6, lane = tid & 63;
    const int q4 = lane >> 4, mm = lane & 15;
    f32x4 acc[4];
#pragma unroll
    for (int nb = 0; nb < 4; ++nb) acc[nb] = (f32x4){0.f, 0.f, 0.f, 0.f};

    const int ar = tid >> 3;
    const int sslot = (tid & 7) ^ (ar & 7);
    const short* Ag = (const short*)A + (size_t)(m0 + ar) * K + sslot * 8;
    const short* Ag2 = (const short*)A + (size_t)(m0 + ar + 32) * K + ((tid & 7) ^ ((ar + 32) & 7)) * 8;
    const short* Bg = (const short*)BT + (size_t)(n0 + ar) * K + sslot * 8;
    const short* Bg2 = (const short*)BT + (size_t)(n0 + ar + 32) * K + ((tid & 7) ^ ((ar + 32) & 7)) * 8;

    const int xm = mm & 7;
    const short* Asf = (const short*)As;
    const short* Bsf = (const short*)Bs;
    const int aoff0 = (w * 16 + mm) * 64 + ((q4 ^ xm)) * 8;
    const int aoff1 = (w * 16 + mm) * 64 + (((4 + q4) ^ xm)) * 8;
    int boff0[4], boff1[4];
#pragma unroll
    for (int nb = 0; nb < 4; ++nb) {
        boff0[nb] = (nb * 16 + mm) * 64 + ((q4 ^ xm)) * 8;
        boff1[nb] = (nb * 16 + mm) * 64 + (((4 + q4) ^ xm)) * 8;
    }

    for (int k0 = 0; k0 < K; k0 += 64) {
        __syncthreads();
        gload16(Ag + k0, &As[ar][(tid & 7) * 8]);
        gload16(Ag2 + k0, &As[ar + 32][(tid & 7) * 8]);
        gload16(Bg + k0, &Bs[ar][(tid & 7) * 8]);
        gload16(Bg2 + k0, &Bs[ar + 32][(tid & 7) * 8]);
        __syncthreads();
        short8 af0 = *(const short8*)(Asf + aoff0);
        short8 af1 = *(const short8*)(Asf + aoff1);
#pragma unroll
        for (int nb = 0; nb < 4; ++nb) {
            short8 b0 = *(const short8*)(Bsf + boff0[nb]);
            short8 b1 = *(const short8*)(Bsf + boff1[nb]);
            acc[nb] = __builtin_amdgcn_mfma_f32_16x16x32_bf16(af0, b0, acc[nb], 0, 0, 0);
            acc[nb] = __builtin_amdgcn_mfma_f32_16x16x32_bf16(af1, b1, acc[nb], 0, 0, 0);
        }
    }

    float vv[4][4];
#pragma unroll
    for (int nb = 0; nb < 4; ++nb)
#pragma unroll
        for (int r = 0; r < 4; ++r)
            vv[nb][r] = acc[nb][r] + bias[n0 + nb * 16 + mm];

    if (isQ || n0 < 256) {
        // per-row RMS norm over the 64-col head tile
#pragma unroll
        for (int r = 0; r < 4; ++r) {
            float ss = 0.f;
#pragma unroll
            for (int nb = 0; nb < 4; ++nb) ss += vv[nb][r] * vv[nb][r];
#pragma unroll
            for (int j = 8; j >= 1; j >>= 1) ss += __shfl_xor(ss, j, 64);
            float rs = 1.0f / sqrtf(ss * (1.0f / 64.0f) + 1e-8f);
            int row = m0 + w * 16 + q4 * 4 + r;
            if (isQ) {
#pragma unroll
                for (int nb = 0; nb < 4; ++nb) {
                    int d = nb * 16 + mm;
                    qh[(size_t)row * DMODEL + n0 + d] =
                        (_Float16)(vv[nb][r] * rs * wn[d] * 0.125f);
                }
            } else {
                int kvh = n0 >> 6;
#pragma unroll
                for (int nb = 0; nb < 4; ++nb) {
                    int d = nb * 16 + mm;
                    kh[((size_t)kvh * TSEQ + row) * HDIM + d] =
                        (_Float16)(vv[nb][r] * rs * wn[d]);
                }
            }
        }
    } else {   // v block
        int kvh = (n0 - 256) >> 6;
#pragma unroll
        for (int r = 0; r < 4; ++r) {
            int row = m0 + w * 16 + q4 * 4 + r;
#pragma unroll
            for (int nb = 0; nb < 4; ++nb)
                vbuf[((size_t)kvh * TSEQ + row) * HDIM + nb * 16 + mm] = vv[nb][r];
        }
    }
}

// ---- out projection GEMM (validated R12/R15: 64x64 tile) ----
__global__ __launch_bounds__(256) void gemm_out(
    const bf16* __restrict__ A, const bf16* __restrict__ BT,
    const float* __restrict__ bias, float* __restrict__ C, int M, int N, int K)
{
    __shared__ short As[64][64];
    __shared__ short Bs[64][64];
    const int tid = threadIdx.x;
    const int m0 = blockIdx.y * 64, n0 = blockIdx.x * 64;
    const int w = tid >> 6, lane = tid & 63;
    const int q4 = lane >> 4, mm = lane & 15;
    f32x4 acc[4];
#pragma unroll
    for (int nb = 0; nb < 4; ++nb) acc[nb] = (f32x4){0.f, 0.f, 0.f, 0.f};

    const int ar = tid >> 3;
    const int sslot = (tid & 7) ^ (ar & 7);
    const short* Ag = (const short*)A + (size_t)(m0 + ar) * K + sslot * 8;
    const short* Ag2 = (const short*)A + (size_t)(m0 + ar + 32) * K + ((tid & 7) ^ ((ar + 32) & 7)) * 8;
    const short* Bg = (const short*)BT + (size_t)(n0 + ar) * K + sslot * 8;
    const short* Bg2 = (const short*)BT + (size_t)(n0 + ar + 32) * K + ((tid & 7) ^ ((ar + 32) & 7)) * 8;

    const int xm = mm & 7;
    const short* Asf = (const short*)As;
    const short* Bsf = (const short*)Bs;
    const int aoff0 = (w * 16 + mm) * 64 + ((q4 ^ xm)) * 8;
    const int aoff1 = (w * 16 + mm) * 64 + (((4 + q4) ^ xm)) * 8;
    int boff0[4], boff1[4];
#pragma unroll
    for (int nb = 0; nb < 4; ++nb) {
        boff0[nb] = (nb * 16 + mm) * 64 + ((q4 ^ xm)) * 8;
        boff1[nb] = (nb * 16 + mm) * 64 + (((4 + q4) ^ xm)) * 8;
    }

    for (int k0 = 0; k0 < K; k0 += 64) {
        __syncthreads();
        gload16(Ag + k0, &As[ar][(tid & 7) * 8]);
        gload16(Ag2 + k0, &As[ar + 32][(tid & 7) * 8]);
        gload16(Bg + k0, &Bs[ar][(tid & 7) * 8]);
        gload16(Bg2 + k0, &Bs[ar + 32][(tid & 7) * 8]);
        __syncthreads();
        short8 af0 = *(const short8*)(Asf + aoff0);
        short8 af1 = *(const short8*)(Asf + aoff1);
#pragma unroll
        for (int nb = 0; nb < 4; ++nb) {
            short8 b0 = *(const short8*)(Bsf + boff0[nb]);
            short8 b1 = *(const short8*)(Bsf + boff1[nb]);
            acc[nb] = __builtin_amdgcn_mfma_f32_16x16x32_bf16(af0, b0, acc[nb], 0, 0, 0);
            acc[nb] = __builtin_amdgcn_mfma_f32_16x16x32_bf16(af1, b1, acc[nb], 0, 0, 0);
        }
    }
#pragma unroll
    for (int nb = 0; nb < 4; ++nb)
#pragma unroll
        for (int r = 0; r < 4; ++r)
            C[(size_t)(m0 + w * 16 + q4 * 4 + r) * N + n0 + nb * 16 + mm]
                = acc[nb][r] + bias[n0 + nb * 16 + mm];
}

// ---- fused MFMA scores + exact top-64 + softmax + V gather ----
// R16 8-row/8-block-per-CU structure with the K-prefetch registers REMOVED
// (K loaded directly in the produce step): cuts ~16 live VGPRs so the
// (256,8) 64-VGPR budget fits without scratch spills (R16: WRITE_SIZE 41MB).
// At 8 blocks/CU the L2 hit latency is TLP-hidden; no software pipelining
// needed. Selection/sort/softmax/gather code per row unchanged (validated).
__global__ __launch_bounds__(256, 8) void attn_kernel(
    const _Float16* __restrict__ qh, const _Float16* __restrict__ kh,
    const float* __restrict__ vbuf, bf16* __restrict__ ybuf,
    const float* __restrict__ kn_w)
{
    __shared__ float Sg[2][8][68];       // [buf][qrow][key] one chunk
    __shared__ float cbS[8][128];        // per-row candidate scores
    __shared__ int   cbI[8][128];        // per-row candidate indices
    __shared__ int   eminS[4];           // per-wave earliest needed key
    const int tid = threadIdx.x;
    const int w = tid >> 6, lane = tid & 63;
    const int mm = lane & 15, q4 = lane >> 4;
    const int h = 15 - (blockIdx.x >> 8);            // heavy (low-slope) heads first
    const int t0 = (255 - (blockIdx.x & 255)) << 3;  // long rows first within head
    const int kvh = h >> 2;
    const float slope = exp2f(-((float)h) * (8.0f / 15.0f));
    const _Float16* kbase = kh + (size_t)kvh * TSEQ * HDIM;
    const int nch = (t0 + 7) >> 6;

    // max |kn_w| (wave-uniform)
    float kw = fabsf(kn_w[lane]);
#pragma unroll
    for (int j = 32; j > 0; j >>= 1) kw = fmaxf(kw, __shfl_xor(kw, j, 64));
    const float kfac = 8.0f * kw * 1.001f;

    // per-row exact bound B and window for this wave's rows r = 2w+rr
    float Brow[2];
    int em = 0x7fffffff;
#pragma unroll
    for (int rr = 0; rr < 2; ++rr) {
        const int r = 2 * w + rr;
        float qe = (float)qh[(size_t)(t0 + r) * DMODEL + h * HDIM + lane];
        float qs = qe * qe;
#pragma unroll
        for (int j = 32; j > 0; j >>= 1) qs += __shfl_xor(qs, j, 64);
        Brow[rr] = sqrtf(qs) * kfac + 1e-3f;
        float Dw = 2.0f * Brow[rr] / slope + 64.0f;
        int e = (int)floorf((float)(t0 + r) - Dw);
        em = min(em, e);
    }
    if (lane == 0) eminS[w] = em;

    // Q fragments: A-frag row mm holds Q row t0+(mm&7) (upper 8 duplicated)
    const _Float16* qp = qh + (size_t)(t0 + (mm & 7)) * DMODEL + h * HDIM + q4 * 8;
    half8 qf0 = *(const half8*)(qp);        // d 0..31
    half8 qf1 = *(const half8*)(qp + 32);   // d 32..63

    // prologue: produce chunk nch into buffer 0 (wave w -> keys w*16..w*16+15)
    {
        const int jb = nch << 6;
        const _Float16* kp = kbase + ((size_t)(jb + w * 16 + mm)) * HDIM + q4 * 8;
        half8 b0 = *(const half8*)(kp);
        half8 b1 = *(const half8*)(kp + 32);
        f32x4 a = __builtin_amdgcn_mfma_f32_16x16x32_f16(
            qf0, b0, (f32x4){0.f, 0.f, 0.f, 0.f}, 0, 0, 0);
        a = __builtin_amdgcn_mfma_f32_16x16x32_f16(qf1, b1, a, 0, 0, 0);
        // C layout: col=lane&15 (key), row=(lane>>4)*4+reg; rows 0..7 valid
        if (q4 < 2) {
#pragma unroll
            for (int rr = 0; rr < 4; ++rr)
                Sg[0][q4 * 4 + rr][w * 16 + mm] = a[rr];
        }
    }
    __syncthreads();

    // block-uniform earliest chunk (conservative: min over all rows)
    int em4 = min(min(eminS[0], eminS[1]), min(eminS[2], eminS[3]));
    const int c_min = (em4 > 0) ? (em4 >> 6) : 0;

    float cs[2]; int ci[2]; float thr[2]; int cnt[2];
#pragma unroll
    for (int rr = 0; rr < 2; ++rr) { cs[rr] = -1e30f; ci[rr] = 0; thr[rr] = -1e30f; cnt[rr] = 0; }

    int p = 0;
    for (int c = nch; c >= c_min; --c) {
        // merge chunk c for this wave's 2 rows
        const int jb = c << 6;
#pragma unroll
        for (int rr = 0; rr < 2; ++rr) {
            const int r = 2 * w + rr;
            // per-row runtime prune (validated): chunk can't reach th
            int dm = (t0 + r - 63) - jb;
            float dmin = (float)(dm > 0 ? dm : 0);
            if (Brow[rr] - slope * dmin < thr[rr]) continue;
            float sr = Sg[p][r][lane];
            int dist = (t0 + r) - (jb + lane);
            float s = sr - slope * (float)dist;
            bool pass = (dist >= 0) && (s >= thr[rr]);
            unsigned long long mk = __ballot(pass);
            if (mk) {
                int rank = __popcll(mk & ((1ull << lane) - 1ull));
                if (pass) { cbS[r][cnt[rr] + rank] = s; cbI[r][cnt[rr] + rank] = jb + lane; }
                cnt[rr] += __popcll(mk);
                if (cnt[rr] >= 64) {
                    float ns = cbS[r][lane];
                    int   ni = cbI[r][lane];
                    bsort(ns, ni, lane);
                    float rsv = __shfl_xor(ns, 63, 64);   // descending view
                    int   riv = __shfl_xor(ni, 63, 64);
                    if (pgt(rsv, riv, cs[rr], ci[rr])) { cs[rr] = rsv; ci[rr] = riv; }
                    bmerge(cs[rr], ci[rr], lane);          // restore ascending
                    thr[rr] = __shfl(cs[rr], 0, 64);
                    int rem = cnt[rr] - 64;
                    float ms = 0.f; int mi = 0;
                    if (lane < rem) { ms = cbS[r][64 + lane]; mi = cbI[r][64 + lane]; }
                    if (lane < rem) { cbS[r][lane] = ms; cbI[r][lane] = mi; }
                    cnt[rr] = rem;
                }
            }
        }
        // produce next chunk into the other buffer (direct load, no prefetch regs)
        const int cn = c - 1;
        if (cn >= c_min) {
            const _Float16* kp = kbase + ((size_t)((cn << 6) + w * 16 + mm)) * HDIM + q4 * 8;
            half8 b0 = *(const half8*)(kp);
            half8 b1 = *(const half8*)(kp + 32);
            f32x4 a = __builtin_amdgcn_mfma_f32_16x16x32_f16(
                qf0, b0, (f32x4){0.f, 0.f, 0.f, 0.f}, 0, 0, 0);
            a = __builtin_amdgcn_mfma_f32_16x16x32_f16(qf1, b1, a, 0, 0, 0);
            if (q4 < 2) {
#pragma unroll
                for (int rr = 0; rr < 4; ++rr)
                    Sg[p ^ 1][q4 * 4 + rr][w * 16 + mm] = a[rr];
            }
        }
        p ^= 1;
        __syncthreads();
    }

    // epilogue per row: flush, softmax, V gather, store
    const float* vb = vbuf + (size_t)kvh * TSEQ * HDIM + lane;
#pragma unroll
    for (int rr = 0; rr < 2; ++rr) {
        const int r = 2 * w + rr;
        if (cnt[rr] > 0) {
            float ns = (lane < cnt[rr]) ? cbS[r][lane] : -2e30f;
            int   ni = (lane < cnt[rr]) ? cbI[r][lane] : 0;
            bsort(ns, ni, lane);
            float rsv = __shfl_xor(ns, 63, 64);
            int   riv = __shfl_xor(ni, 63, 64);
            if (pgt(rsv, riv, cs[rr], ci[rr])) { cs[rr] = rsv; ci[rr] = riv; }
            bmerge(cs[rr], ci[rr], lane);
        }
        // softmax over kept 64 (pads -1e30 -> weight 0); max at lane 63
        float msx = __shfl(cs[rr], 63, 64);
        bool valid = cs[rr] > -1e29f;
        float pr = valid ? __expf(cs[rr] - msx) : 0.f;
        float l = pr;
#pragma unroll
        for (int j2 = 32; j2 > 0; j2 >>= 1) l += __shfl_xor(l, j2, 64);
        float wgt = pr / l;
        int widx = valid ? ci[rr] : 0;
        float acc = 0.f;
#pragma unroll 8
        for (int i = 0; i < 64; ++i) {
            float wv = __shfl(wgt, i, 64);
            int  ix = __shfl(widx, i, 64);
            acc += wv * vb[(size_t)ix * HDIM];
        }
        ybuf[(size_t)(t0 + r) * DMODEL + h * HDIM + lane] = __float2bfloat16(acc);
    }
}

extern "C" void kernel_launch(void* const* d_in, const int* in_sizes, int n_in,
                              void* d_out, int out_size, void* d_ws, size_t ws_size,
                              hipStream_t stream)
{
    // d_in order: x, wq, bq, wkv, bkv, wo, bo, qn_w, kn_w  (all fp32)
    const float* x    = (const float*)d_in[0];
    const float* wq   = (const float*)d_in[1];
    const float* bq   = (const float*)d_in[2];
    const float* wkv  = (const float*)d_in[3];
    const float* bkv  = (const float*)d_in[4];
    const float* wo   = (const float*)d_in[5];
    const float* bo   = (const float*)d_in[6];
    const float* qn_w = (const float*)d_in[7];
    const float* kn_w = (const float*)d_in[8];
    char* ws = (char*)d_ws;
    // ws layout (28 MB):
    // cx bf16 4M @0 | cwqT 2M @4M | cwkvT 1M @6M | cwoT 2M @7M |
    // qh f16 4M @9M | kh f16 1M @21M | vbuf fp32 2M @22M |
    // ybuf bf16 4M @24M..28M  (no overlaps)
    bf16*      cx    = (bf16*)(ws);
    bf16*      cwqT  = (bf16*)(ws + ((size_t)4  << 20));   // [1024][1024] (n,k)
    bf16*      cwkvT = (bf16*)(ws + ((size_t)6  << 20));   // [512][1024]  (n,k)
    bf16*      cwoT  = (bf16*)(ws + ((size_t)7  << 20));   // [1024][1024] (n,k)
    _Float16*  qh    = (_Float16*)(ws + ((size_t)9  << 20));
    _Float16*  kh    = (_Float16*)(ws + ((size_t)21 << 20));
    float*     vbuf  = (float*)(ws + ((size_t)22 << 20));
    bf16*      ybuf  = (bf16*)(ws + ((size_t)24 << 20));
    float*     out   = (float*)d_out;   // fp32 output

    prep_kernel<<<3584, 256, 0, stream>>>(x, wq, wkv, wo, cx, cwqT, cwkvT, cwoT);
    gemm_qkv<<<dim3(24, TSEQ / 64), 256, 0, stream>>>(
        cx, cwqT, cwkvT, bq, bkv, qh, kh, vbuf, qn_w, kn_w);
    attn_kernel<<<NH * (TSEQ / 8), 256, 0, stream>>>(qh, kh, vbuf, ybuf, kn_w);
    gemm_out<<<dim3(DMODEL / 64, TSEQ / 64), 256, 0, stream>>>(
        ybuf, cwoT, bo, out, TSEQ, DMODEL, DMODEL);
}

// Round 18
// 187.334 us; speedup vs baseline: 1.3434x; 1.2342x over previous
//
#include <hip/hip_runtime.h>
#include <hip/hip_bf16.h>
#include <stdint.h>

// Problem constants (fixed by reference)
#define TSEQ   2048
#define DMODEL 1024
#define NH     16
#define HDIM   64
#define NKVH   4

typedef __attribute__((ext_vector_type(8))) short short8;
typedef __attribute__((ext_vector_type(8))) _Float16 half8;
typedef __attribute__((ext_vector_type(4))) float f32x4;
typedef __hip_bfloat16 bf16;

// async global->LDS, 16B per lane (linear LDS dest = wave base + lane*16)
__device__ __forceinline__ void gload16(const void* g, void* l) {
    __builtin_amdgcn_global_load_lds(
        (const __attribute__((address_space(1))) uint32_t*)g,
        (__attribute__((address_space(3))) uint32_t*)l, 16, 0, 0);
}

// ---- packed selection key: monotone(f32 score) top-21 bits | (2047-idx) ----
// Total order: higher score wins; equal truncated score -> lower idx wins
// (matches jax stable top_k; truncation 2^-12 rel, below existing f16 noise).
__device__ __forceinline__ uint32_t packkey(float s, int idx) {
    uint32_t fb = __float_as_uint(s);
    uint32_t mono = fb ^ (uint32_t)(((int)fb >> 31) | 0x80000000);
    return (mono & 0xFFFFF800u) | (uint32_t)(2047 - idx);
}
__device__ __forceinline__ float unpacks(uint32_t key) {
    uint32_t mono = key & 0xFFFFF800u;
    uint32_t fb = (mono & 0x80000000u) ? (mono ^ 0x80000000u) : ~mono;
    return __uint_as_float(fb);
}
__device__ __forceinline__ int unpacki(uint32_t key) {
    return 2047 - (int)(key & 0x7FFu);
}

// full bitonic sort across 64 lanes, ascending by packed key (min/max network)
__device__ __forceinline__ void bsortK(uint32_t& kk, int lane) {
#pragma unroll
    for (int k = 2; k <= 64; k <<= 1) {
#pragma unroll
        for (int j = k >> 1; j > 0; j >>= 1) {
            uint32_t o = (uint32_t)__shfl_xor((int)kk, j, 64);
            bool wmin = ((lane & j) == 0) == ((lane & k) == 0);
            kk = wmin ? min(kk, o) : max(kk, o);
        }
    }
}
// bitonic -> ascending cleanup (6 stages)
__device__ __forceinline__ void bmergeK(uint32_t& kk, int lane) {
#pragma unroll
    for (int j = 32; j > 0; j >>= 1) {
        uint32_t o = (uint32_t)__shfl_xor((int)kk, j, 64);
        kk = ((lane & j) == 0) ? min(kk, o) : max(kk, o);
    }
}

// ---- fused prep: fp32->bf16 convert x, transpose-convert the three weights ----
__global__ __launch_bounds__(256) void prep_kernel(
    const float* __restrict__ x, const float* __restrict__ wq,
    const float* __restrict__ wkv, const float* __restrict__ wo,
    bf16* __restrict__ cx, bf16* __restrict__ cwqT,
    bf16* __restrict__ cwkvT, bf16* __restrict__ cwoT)
{
    __shared__ float tile[32][33];
    const int bid = blockIdx.x;
    if (bid < 1024) {
        const size_t i0 = (size_t)bid * 256 + threadIdx.x;
        for (size_t i = i0; i < 2097152; i += 262144) cx[i] = __float2bfloat16(x[i]);
        return;
    }
    const float* in; bf16* out; int R, Cc, bx, by;
    if (bid < 2048) {        // wq: 1024x1024
        int idx = bid - 1024; in = wq; out = cwqT; R = 1024; Cc = 1024;
        bx = (idx & 31) << 5; by = (idx >> 5) << 5;
    } else if (bid < 2560) { // wkv: 1024x512
        int idx = bid - 2048; in = wkv; out = cwkvT; R = 1024; Cc = 512;
        bx = (idx & 15) << 5; by = (idx >> 4) << 5;
    } else {                 // wo: 1024x1024
        int idx = bid - 2560; in = wo; out = cwoT; R = 1024; Cc = 1024;
        bx = (idx & 31) << 5; by = (idx >> 5) << 5;
    }
    const int tx = threadIdx.x & 31, ty = threadIdx.x >> 5;   // 32 x 8
#pragma unroll
    for (int i = 0; i < 32; i += 8)
        tile[ty + i][tx] = in[(size_t)(by + ty + i) * Cc + bx + tx];
    __syncthreads();
#pragma unroll
    for (int i = 0; i < 32; i += 8)
        out[(size_t)(bx + ty + i) * R + by + tx] = __float2bfloat16(tile[tx][ty + i]);
}

// ---- fused Q+KV GEMM (validated R12/R15): one launch; bx<16 = Q
//      (RMSnorm*0.125 -> qh), bx>=16 = KV (k: RMSnorm -> kh; v -> vbuf).
__global__ __launch_bounds__(256) void gemm_qkv(
    const bf16* __restrict__ A, const bf16* __restrict__ BTq,
    const bf16* __restrict__ BTkv, const float* __restrict__ bq,
    const float* __restrict__ bkv, _Float16* __restrict__ qh,
    _Float16* __restrict__ kh, float* __restrict__ vbuf,
    const float* __restrict__ qn_w, const float* __restrict__ kn_w)
{
    __shared__ short As[64][64];
    __shared__ short Bs[64][64];
    const int tid = threadIdx.x;
    const int bx = blockIdx.x;
    const bool isQ = bx < 16;
    const bf16* BT = isQ ? BTq : BTkv;
    const float* bias = isQ ? bq : bkv;
    const float* wn = isQ ? qn_w : kn_w;
    const int n0 = (isQ ? bx : bx - 16) * 64;
    const int K = 1024;
    const int m0 = blockIdx.y * 64;
    const int w = tid >> 6, lane = tid & 63;
    const int q4 = lane >> 4, mm = lane & 15;
    f32x4 acc[4];
#pragma unroll
    for (int nb = 0; nb < 4; ++nb) acc[nb] = (f32x4){0.f, 0.f, 0.f, 0.f};

    const int ar = tid >> 3;
    const int sslot = (tid & 7) ^ (ar & 7);
    const short* Ag = (const short*)A + (size_t)(m0 + ar) * K + sslot * 8;
    const short* Ag2 = (const short*)A + (size_t)(m0 + ar + 32) * K + ((tid & 7) ^ ((ar + 32) & 7)) * 8;
    const short* Bg = (const short*)BT + (size_t)(n0 + ar) * K + sslot * 8;
    const short* Bg2 = (const short*)BT + (size_t)(n0 + ar + 32) * K + ((tid & 7) ^ ((ar + 32) & 7)) * 8;

    const int xm = mm & 7;
    const short* Asf = (const short*)As;
    const short* Bsf = (const short*)Bs;
    const int aoff0 = (w * 16 + mm) * 64 + ((q4 ^ xm)) * 8;
    const int aoff1 = (w * 16 + mm) * 64 + (((4 + q4) ^ xm)) * 8;
    int boff0[4], boff1[4];
#pragma unroll
    for (int nb = 0; nb < 4; ++nb) {
        boff0[nb] = (nb * 16 + mm) * 64 + ((q4 ^ xm)) * 8;
        boff1[nb] = (nb * 16 + mm) * 64 + (((4 + q4) ^ xm)) * 8;
    }

    for (int k0 = 0; k0 < K; k0 += 64) {
        __syncthreads();
        gload16(Ag + k0, &As[ar][(tid & 7) * 8]);
        gload16(Ag2 + k0, &As[ar + 32][(tid & 7) * 8]);
        gload16(Bg + k0, &Bs[ar][(tid & 7) * 8]);
        gload16(Bg2 + k0, &Bs[ar + 32][(tid & 7) * 8]);
        __syncthreads();
        short8 af0 = *(const short8*)(Asf + aoff0);
        short8 af1 = *(const short8*)(Asf + aoff1);
#pragma unroll
        for (int nb = 0; nb < 4; ++nb) {
            short8 b0 = *(const short8*)(Bsf + boff0[nb]);
            short8 b1 = *(const short8*)(Bsf + boff1[nb]);
            acc[nb] = __builtin_amdgcn_mfma_f32_16x16x32_bf16(af0, b0, acc[nb], 0, 0, 0);
            acc[nb] = __builtin_amdgcn_mfma_f32_16x16x32_bf16(af1, b1, acc[nb], 0, 0, 0);
        }
    }

    float vv[4][4];
#pragma unroll
    for (int nb = 0; nb < 4; ++nb)
#pragma unroll
        for (int r = 0; r < 4; ++r)
            vv[nb][r] = acc[nb][r] + bias[n0 + nb * 16 + mm];

    if (isQ || n0 < 256) {
        // per-row RMS norm over the 64-col head tile
#pragma unroll
        for (int r = 0; r < 4; ++r) {
            float ss = 0.f;
#pragma unroll
            for (int nb = 0; nb < 4; ++nb) ss += vv[nb][r] * vv[nb][r];
#pragma unroll
            for (int j = 8; j >= 1; j >>= 1) ss += __shfl_xor(ss, j, 64);
            float rs = 1.0f / sqrtf(ss * (1.0f / 64.0f) + 1e-8f);
            int row = m0 + w * 16 + q4 * 4 + r;
            if (isQ) {
#pragma unroll
                for (int nb = 0; nb < 4; ++nb) {
                    int d = nb * 16 + mm;
                    qh[(size_t)row * DMODEL + n0 + d] =
                        (_Float16)(vv[nb][r] * rs * wn[d] * 0.125f);
                }
            } else {
                int kvh = n0 >> 6;
#pragma unroll
                for (int nb = 0; nb < 4; ++nb) {
                    int d = nb * 16 + mm;
                    kh[((size_t)kvh * TSEQ + row) * HDIM + d] =
                        (_Float16)(vv[nb][r] * rs * wn[d]);
                }
            }
        }
    } else {   // v block
        int kvh = (n0 - 256) >> 6;
#pragma unroll
        for (int r = 0; r < 4; ++r) {
            int row = m0 + w * 16 + q4 * 4 + r;
#pragma unroll
            for (int nb = 0; nb < 4; ++nb)
                vbuf[((size_t)kvh * TSEQ + row) * HDIM + nb * 16 + mm] = vv[nb][r];
        }
    }
}

// ---- out projection GEMM (validated R12/R15: 64x64 tile) ----
__global__ __launch_bounds__(256) void gemm_out(
    const bf16* __restrict__ A, const bf16* __restrict__ BT,
    const float* __restrict__ bias, float* __restrict__ C, int M, int N, int K)
{
    __shared__ short As[64][64];
    __shared__ short Bs[64][64];
    const int tid = threadIdx.x;
    const int m0 = blockIdx.y * 64, n0 = blockIdx.x * 64;
    const int w = tid >> 6, lane = tid & 63;
    const int q4 = lane >> 4, mm = lane & 15;
    f32x4 acc[4];
#pragma unroll
    for (int nb = 0; nb < 4; ++nb) acc[nb] = (f32x4){0.f, 0.f, 0.f, 0.f};

    const int ar = tid >> 3;
    const int sslot = (tid & 7) ^ (ar & 7);
    const short* Ag = (const short*)A + (size_t)(m0 + ar) * K + sslot * 8;
    const short* Ag2 = (const short*)A + (size_t)(m0 + ar + 32) * K + ((tid & 7) ^ ((ar + 32) & 7)) * 8;
    const short* Bg = (const short*)BT + (size_t)(n0 + ar) * K + sslot * 8;
    const short* Bg2 = (const short*)BT + (size_t)(n0 + ar + 32) * K + ((tid & 7) ^ ((ar + 32) & 7)) * 8;

    const int xm = mm & 7;
    const short* Asf = (const short*)As;
    const short* Bsf = (const short*)Bs;
    const int aoff0 = (w * 16 + mm) * 64 + ((q4 ^ xm)) * 8;
    const int aoff1 = (w * 16 + mm) * 64 + (((4 + q4) ^ xm)) * 8;
    int boff0[4], boff1[4];
#pragma unroll
    for (int nb = 0; nb < 4; ++nb) {
        boff0[nb] = (nb * 16 + mm) * 64 + ((q4 ^ xm)) * 8;
        boff1[nb] = (nb * 16 + mm) * 64 + (((4 + q4) ^ xm)) * 8;
    }

    for (int k0 = 0; k0 < K; k0 += 64) {
        __syncthreads();
        gload16(Ag + k0, &As[ar][(tid & 7) * 8]);
        gload16(Ag2 + k0, &As[ar + 32][(tid & 7) * 8]);
        gload16(Bg + k0, &Bs[ar][(tid & 7) * 8]);
        gload16(Bg2 + k0, &Bs[ar + 32][(tid & 7) * 8]);
        __syncthreads();
        short8 af0 = *(const short8*)(Asf + aoff0);
        short8 af1 = *(const short8*)(Asf + aoff1);
#pragma unroll
        for (int nb = 0; nb < 4; ++nb) {
            short8 b0 = *(const short8*)(Bsf + boff0[nb]);
            short8 b1 = *(const short8*)(Bsf + boff1[nb]);
            acc[nb] = __builtin_amdgcn_mfma_f32_16x16x32_bf16(af0, b0, acc[nb], 0, 0, 0);
            acc[nb] = __builtin_amdgcn_mfma_f32_16x16x32_bf16(af1, b1, acc[nb], 0, 0, 0);
        }
    }
#pragma unroll
    for (int nb = 0; nb < 4; ++nb)
#pragma unroll
        for (int r = 0; r < 4; ++r)
            C[(size_t)(m0 + w * 16 + q4 * 4 + r) * N + n0 + nb * 16 + mm]
                = acc[nb][r] + bias[n0 + nb * 16 + mm];
}

// ---- fused MFMA scores + exact top-64 + softmax + V gather ----
// R17 structure (8-row blocks, 8 blocks/CU, direct K loads) with PACKED-KEY
// selection: (score,idx) in one monotone u32 -> bitonic stage = 1 ds_bpermute
// + v_min/v_max (vs 2 bpermute + 5-op pgt comparator). Gather broadcast is a
// single packed u32 (wgt-trunc | idx). Same selection semantics to 2^-12
// score truncation (ties -> lower idx, jax rule).
__global__ __launch_bounds__(256, 8) void attn_kernel(
    const _Float16* __restrict__ qh, const _Float16* __restrict__ kh,
    const float* __restrict__ vbuf, bf16* __restrict__ ybuf,
    const float* __restrict__ kn_w)
{
    __shared__ float    Sg[2][8][68];    // [buf][qrow][key] one chunk
    __shared__ uint32_t cbK[8][128];     // per-row candidate packed keys
    __shared__ int      eminS[4];        // per-wave earliest needed key
    const int tid = threadIdx.x;
    const int w = tid >> 6, lane = tid & 63;
    const int mm = lane & 15, q4 = lane >> 4;
    const int h = 15 - (blockIdx.x >> 8);            // heavy (low-slope) heads first
    const int t0 = (255 - (blockIdx.x & 255)) << 3;  // long rows first within head
    const int kvh = h >> 2;
    const float slope = exp2f(-((float)h) * (8.0f / 15.0f));
    const _Float16* kbase = kh + (size_t)kvh * TSEQ * HDIM;
    const int nch = (t0 + 7) >> 6;
    const uint32_t PADK   = packkey(-1e30f, 0);
    const uint32_t VALIDT = packkey(-1e29f, 2047);

    // max |kn_w| (wave-uniform)
    float kw = fabsf(kn_w[lane]);
#pragma unroll
    for (int j = 32; j > 0; j >>= 1) kw = fmaxf(kw, __shfl_xor(kw, j, 64));
    const float kfac = 8.0f * kw * 1.001f;

    // per-row exact bound B and window for this wave's rows r = 2w+rr
    float Brow[2];
    int em = 0x7fffffff;
#pragma unroll
    for (int rr = 0; rr < 2; ++rr) {
        const int r = 2 * w + rr;
        float qe = (float)qh[(size_t)(t0 + r) * DMODEL + h * HDIM + lane];
        float qs = qe * qe;
#pragma unroll
        for (int j = 32; j > 0; j >>= 1) qs += __shfl_xor(qs, j, 64);
        Brow[rr] = sqrtf(qs) * kfac + 1e-3f;
        float Dw = 2.0f * Brow[rr] / slope + 64.0f;
        int e = (int)floorf((float)(t0 + r) - Dw);
        em = min(em, e);
    }
    if (lane == 0) eminS[w] = em;

    // Q fragments: A-frag row mm holds Q row t0+(mm&7) (upper 8 duplicated)
    const _Float16* qp = qh + (size_t)(t0 + (mm & 7)) * DMODEL + h * HDIM + q4 * 8;
    half8 qf0 = *(const half8*)(qp);        // d 0..31
    half8 qf1 = *(const half8*)(qp + 32);   // d 32..63

    // prologue: produce chunk nch into buffer 0 (wave w -> keys w*16..w*16+15)
    {
        const int jb = nch << 6;
        const _Float16* kp = kbase + ((size_t)(jb + w * 16 + mm)) * HDIM + q4 * 8;
        half8 b0 = *(const half8*)(kp);
        half8 b1 = *(const half8*)(kp + 32);
        f32x4 a = __builtin_amdgcn_mfma_f32_16x16x32_f16(
            qf0, b0, (f32x4){0.f, 0.f, 0.f, 0.f}, 0, 0, 0);
        a = __builtin_amdgcn_mfma_f32_16x16x32_f16(qf1, b1, a, 0, 0, 0);
        // C layout: col=lane&15 (key), row=(lane>>4)*4+reg; rows 0..7 valid
        if (q4 < 2) {
#pragma unroll
            for (int rr = 0; rr < 4; ++rr)
                Sg[0][q4 * 4 + rr][w * 16 + mm] = a[rr];
        }
    }
    __syncthreads();

    // block-uniform earliest chunk (conservative: min over all rows)
    int em4 = min(min(eminS[0], eminS[1]), min(eminS[2], eminS[3]));
    const int c_min = (em4 > 0) ? (em4 >> 6) : 0;

    uint32_t csK[2]; uint32_t thK[2]; float thr[2]; int cnt[2];
#pragma unroll
    for (int rr = 0; rr < 2; ++rr) { csK[rr] = PADK; thK[rr] = PADK; thr[rr] = -1e30f; cnt[rr] = 0; }

    int p = 0;
    for (int c = nch; c >= c_min; --c) {
        // merge chunk c for this wave's 2 rows
        const int jb = c << 6;
#pragma unroll
        for (int rr = 0; rr < 2; ++rr) {
            const int r = 2 * w + rr;
            // per-row runtime prune (validated): chunk can't reach th
            int dm = (t0 + r - 63) - jb;
            float dmin = (float)(dm > 0 ? dm : 0);
            if (Brow[rr] - slope * dmin < thr[rr]) continue;
            float sr = Sg[p][r][lane];
            int dist = (t0 + r) - (jb + lane);
            float s = sr - slope * (float)dist;
            uint32_t kc = packkey(s, jb + lane);
            bool pass = (dist >= 0) && (kc >= thK[rr]);
            unsigned long long mk = __ballot(pass);
            if (mk) {
                int rank = __popcll(mk & ((1ull << lane) - 1ull));
                if (pass) cbK[r][cnt[rr] + rank] = kc;
                cnt[rr] += __popcll(mk);
                if (cnt[rr] >= 64) {
                    uint32_t nk = cbK[r][lane];
                    bsortK(nk, lane);
                    uint32_t rv = (uint32_t)__shfl_xor((int)nk, 63, 64);  // desc view
                    csK[rr] = max(csK[rr], rv);
                    bmergeK(csK[rr], lane);                // restore ascending
                    thK[rr] = (uint32_t)__shfl((int)csK[rr], 0, 64);
                    thr[rr] = unpacks(thK[rr]);
                    int rem = cnt[rr] - 64;
                    uint32_t mv = 0u;
                    if (lane < rem) mv = cbK[r][64 + lane];
                    if (lane < rem) cbK[r][lane] = mv;
                    cnt[rr] = rem;
                }
            }
        }
        // produce next chunk into the other buffer (direct load, no prefetch regs)
        const int cn = c - 1;
        if (cn >= c_min) {
            const _Float16* kp = kbase + ((size_t)((cn << 6) + w * 16 + mm)) * HDIM + q4 * 8;
            half8 b0 = *(const half8*)(kp);
            half8 b1 = *(const half8*)(kp + 32);
            f32x4 a = __builtin_amdgcn_mfma_f32_16x16x32_f16(
                qf0, b0, (f32x4){0.f, 0.f, 0.f, 0.f}, 0, 0, 0);
            a = __builtin_amdgcn_mfma_f32_16x16x32_f16(qf1, b1, a, 0, 0, 0);
            if (q4 < 2) {
#pragma unroll
                for (int rr = 0; rr < 4; ++rr)
                    Sg[p ^ 1][q4 * 4 + rr][w * 16 + mm] = a[rr];
            }
        }
        p ^= 1;
        __syncthreads();
    }

    // epilogue per row: flush, softmax, V gather, store
    const float* vb = vbuf + (size_t)kvh * TSEQ * HDIM + lane;
#pragma unroll
    for (int rr = 0; rr < 2; ++rr) {
        const int r = 2 * w + rr;
        if (cnt[rr] > 0) {
            uint32_t nk = (lane < cnt[rr]) ? cbK[r][lane] : 0u;  // 0 < any real key
            bsortK(nk, lane);
            uint32_t rv = (uint32_t)__shfl_xor((int)nk, 63, 64);
            csK[rr] = max(csK[rr], rv);
            bmergeK(csK[rr], lane);
        }
        // softmax over kept 64 (pads -> weight 0); max key at lane 63
        uint32_t kk = csK[rr];
        float sx = unpacks((uint32_t)__shfl((int)kk, 63, 64));
        bool valid = kk > VALIDT;
        float s = unpacks(kk);
        float pr = valid ? __expf(s - sx) : 0.f;
        float l = pr;
#pragma unroll
        for (int j2 = 32; j2 > 0; j2 >>= 1) l += __shfl_xor(l, j2, 64);
        float wgt = pr / l;
        int widx = valid ? unpacki(kk) : 0;
        // packed gather broadcast: wgt truncated to top 21 bits | idx (11 bits)
        uint32_t g = (__float_as_uint(wgt) & 0xFFFFF800u) | (uint32_t)widx;
        float acc = 0.f;
#pragma unroll 8
        for (int i = 0; i < 64; ++i) {
            uint32_t gb = (uint32_t)__shfl((int)g, i, 64);
            float wv = __uint_as_float(gb & 0xFFFFF800u);
            int  ix = (int)(gb & 0x7FFu);
            acc += wv * vb[(size_t)ix * HDIM];
        }
        ybuf[(size_t)(t0 + r) * DMODEL + h * HDIM + lane] = __float2bfloat16(acc);
    }
}

extern "C" void kernel_launch(void* const* d_in, const int* in_sizes, int n_in,
                              void* d_out, int out_size, void* d_ws, size_t ws_size,
                              hipStream_t stream)
{
    // d_in order: x, wq, bq, wkv, bkv, wo, bo, qn_w, kn_w  (all fp32)
    const float* x    = (const float*)d_in[0];
    const float* wq   = (const float*)d_in[1];
    const float* bq   = (const float*)d_in[2];
    const float* wkv  = (const float*)d_in[3];
    const float* bkv  = (const float*)d_in[4];
    const float* wo   = (const float*)d_in[5];
    const float* bo   = (const float*)d_in[6];
    const float* qn_w = (const float*)d_in[7];
    const float* kn_w = (const float*)d_in[8];
    char* ws = (char*)d_ws;
    // ws layout (28 MB):
    // cx bf16 4M @0 | cwqT 2M @4M | cwkvT 1M @6M | cwoT 2M @7M |
    // qh f16 4M @9M | kh f16 1M @21M | vbuf fp32 2M @22M |
    // ybuf bf16 4M @24M..28M  (no overlaps)
    bf16*      cx    = (bf16*)(ws);
    bf16*      cwqT  = (bf16*)(ws + ((size_t)4  << 20));   // [1024][1024] (n,k)
    bf16*      cwkvT = (bf16*)(ws + ((size_t)6  << 20));   // [512][1024]  (n,k)
    bf16*      cwoT  = (bf16*)(ws + ((size_t)7  << 20));   // [1024][1024] (n,k)
    _Float16*  qh    = (_Float16*)(ws + ((size_t)9  << 20));
    _Float16*  kh    = (_Float16*)(ws + ((size_t)21 << 20));
    float*     vbuf  = (float*)(ws + ((size_t)22 << 20));
    bf16*      ybuf  = (bf16*)(ws + ((size_t)24 << 20));
    float*     out   = (float*)d_out;   // fp32 output

    prep_kernel<<<3584, 256, 0, stream>>>(x, wq, wkv, wo, cx, cwqT, cwkvT, cwoT);
    gemm_qkv<<<dim3(24, TSEQ / 64), 256, 0, stream>>>(
        cx, cwqT, cwkvT, bq, bkv, qh, kh, vbuf, qn_w, kn_w);
    attn_kernel<<<NH * (TSEQ / 8), 256, 0, stream>>>(qh, kh, vbuf, ybuf, kn_w);
    gemm_out<<<dim3(DMODEL / 64, TSEQ / 64), 256, 0, stream>>>(
        ybuf, cwoT, bo, out, TSEQ, DMODEL, DMODEL);
}